// Round 16
// baseline (221.029 us; speedup 1.0000x reference)
//
#include <hip/hip_runtime.h>
#include <hip/hip_bf16.h>

#define DD   256
#define NH   8
#define HDIM 32
#define LV   4
#define NP   4
#define DFF  2048
#define BB   4
#define NQQ  900
#define SS   21760

typedef __bf16 bf16x8 __attribute__((ext_vector_type(8)));
typedef __bf16 bf16x2 __attribute__((ext_vector_type(2)));
typedef float  f32x4  __attribute__((ext_vector_type(4)));

__device__ inline void stval(float* p, float v) { *p = v; }
__device__ inline void stval(__bf16* p, float v) { *p = (__bf16)v; }

__device__ __forceinline__ void gload16(const void* g, void* l) {
    __builtin_amdgcn_global_load_lds(
        (const __attribute__((address_space(1))) void*)g,
        (__attribute__((address_space(3))) void*)l, 16, 0, 0);
}

// ============ all weight transposes in ONE launch ============================
struct TPtrs {
    const float* s[10];
    __bf16* d[10];
};

__global__ void transp_all(TPtrs P) {
    const int Ks[10] = {256, 256, 256, 256, 256, 256, 256, 256, 256, 2048};
    const int Ns[10] = {256, 256, 256, 256, 256, 256, 128, 256, 2048, 256};
    const int tiles[10] = {64, 64, 64, 64, 64, 64, 32, 64, 512, 512};
    int t = blockIdx.x;
    int j = 0, base = 0;
    while (t >= base + tiles[j]) { base += tiles[j]; j++; }
    int lt = t - base;
    int K = Ks[j], N = Ns[j];
    int tn = N >> 5;
    int nb = (lt % tn) * 32, kb = (lt / tn) * 32;
    const float* W = P.s[j];
    __bf16* Wt = P.d[j];
    __shared__ float tbuf[32][33];
    for (int i = threadIdx.y; i < 32; i += 8)
        tbuf[i][threadIdx.x] = W[(size_t)(kb + i) * N + nb + threadIdx.x];
    __syncthreads();
    for (int i = threadIdx.y; i < 32; i += 8)
        Wt[(size_t)(nb + i) * K + kb + threadIdx.x] = (__bf16)tbuf[threadIdx.x][i];
}

// ============ GEMM body (device fn): C = (A[+A2]) @ Wt^T + bias [opt LN] ====
#define BM 64
#define BN 64
#define BKK 64

template <typename AT, typename OT, int RELU, int NSUB, bool LNF>
__device__ __forceinline__ void gemm_body(
    int bx, int by, char* ldsraw,
    const AT* __restrict__ A, const float* __restrict__ A2,
    const __bf16* __restrict__ Wt,
    const float* __restrict__ bias, const float* __restrict__ bias2, int nsplit,
    const float* __restrict__ res, const float* __restrict__ lng,
    const float* __restrict__ lnb,
    OT* __restrict__ C, int M, int N, int K) {
    int tid = threadIdx.x;
    int lane = tid & 63;
    int wave = tid >> 6;
    int wr = wave >> 1, wc = wave & 1;
    int m0 = by * BM;
    int n0 = bx * (BN * NSUB);

    __bf16* As = (__bf16*)ldsraw;
    __bf16* Bs = (__bf16*)(ldsraw + BM * BKK * 2);
    float* rsum  = (float*)(ldsraw + BM * BKK * 2 + NSUB * BN * BKK * 2);
    float* rsum2 = rsum + 128;

    f32x4 acc[NSUB][2][2] = {};

    int srow = tid >> 2;
    int sq = tid & 3;
    int u0 = sq << 1;
    int p0 = (u0 ^ (srow & 7)) * 8;
    int p1 = ((u0 + 1) ^ (srow & 7)) * 8;
    int fr = lane & 15, gq = lane >> 4;

    for (int k0 = 0; k0 < K; k0 += BKK) {
        {
            int gm = m0 + srow;
            bf16x8 v0 = {}, v1 = {};
            if (gm < M) {
                if constexpr (sizeof(AT) == 4) {
                    const float* ap = (const float*)A + (size_t)gm * K + k0 + sq * 16;
                    f32x4 f0 = *(const f32x4*)(ap + 0);
                    f32x4 f1 = *(const f32x4*)(ap + 4);
                    f32x4 f2 = *(const f32x4*)(ap + 8);
                    f32x4 f3 = *(const f32x4*)(ap + 12);
                    if (A2) {
                        const float* ap2 = A2 + (size_t)gm * K + k0 + sq * 16;
                        f0 += *(const f32x4*)(ap2 + 0);
                        f1 += *(const f32x4*)(ap2 + 4);
                        f2 += *(const f32x4*)(ap2 + 8);
                        f3 += *(const f32x4*)(ap2 + 12);
                    }
#pragma unroll
                    for (int e = 0; e < 4; e++) {
                        v0[e] = (__bf16)f0[e]; v0[e + 4] = (__bf16)f1[e];
                        v1[e] = (__bf16)f2[e]; v1[e + 4] = (__bf16)f3[e];
                    }
                } else {
                    const __bf16* ap = (const __bf16*)A + (size_t)gm * K + k0 + sq * 16;
                    v0 = *(const bf16x8*)(ap);
                    v1 = *(const bf16x8*)(ap + 8);
                }
            }
            *(bf16x8*)(&As[srow * 64 + p0]) = v0;
            *(bf16x8*)(&As[srow * 64 + p1]) = v1;
        }
#pragma unroll
        for (int ns = 0; ns < NSUB; ns++) {
            int gn = n0 + ns * BN + srow;
            const __bf16* bp = Wt + (size_t)gn * K + k0 + sq * 16;
            bf16x8 w0 = *(const bf16x8*)(bp);
            bf16x8 w1 = *(const bf16x8*)(bp + 8);
            *(bf16x8*)(&Bs[ns * BN * BKK + srow * 64 + p0]) = w0;
            *(bf16x8*)(&Bs[ns * BN * BKK + srow * 64 + p1]) = w1;
        }
        __syncthreads();
#pragma unroll
        for (int ks = 0; ks < 2; ks++) {
            bf16x8 a[2];
#pragma unroll
            for (int i = 0; i < 2; i++) {
                int ma = wr * 32 + i * 16 + fr;
                a[i] = *(const bf16x8*)(&As[ma * 64 + ((ks * 4 + gq) ^ (ma & 7)) * 8]);
            }
#pragma unroll
            for (int ns = 0; ns < NSUB; ns++) {
                bf16x8 b[2];
#pragma unroll
                for (int j = 0; j < 2; j++) {
                    int nb = wc * 32 + j * 16 + fr;
                    b[j] = *(const bf16x8*)(&Bs[ns * BN * BKK + nb * 64 + ((ks * 4 + gq) ^ (nb & 7)) * 8]);
                }
#pragma unroll
                for (int i = 0; i < 2; i++)
#pragma unroll
                    for (int j = 0; j < 2; j++)
                        acc[ns][i][j] = __builtin_amdgcn_mfma_f32_16x16x32_bf16(a[i], b[j], acc[ns][i][j], 0, 0, 0);
            }
        }
        __syncthreads();
    }
    int orow = gq * 4;
    if constexpr (!LNF) {
#pragma unroll
        for (int ns = 0; ns < NSUB; ns++)
#pragma unroll
            for (int i = 0; i < 2; i++)
#pragma unroll
                for (int j = 0; j < 2; j++) {
                    int gn = n0 + ns * BN + wc * 32 + j * 16 + fr;
                    float bv = (gn < nsplit) ? bias[gn] : bias2[gn - nsplit];
#pragma unroll
                    for (int r = 0; r < 4; r++) {
                        int gm = m0 + wr * 32 + i * 16 + orow + r;
                        if (gm < M) {
                            float v = acc[ns][i][j][r] + bv;
                            if (RELU) v = fmaxf(v, 0.f);
                            stval(C + (size_t)gm * N + gn, v);
                        }
                    }
                }
    } else {
        float part[2][4] = {};
#pragma unroll
        for (int ns = 0; ns < NSUB; ns++)
#pragma unroll
            for (int i = 0; i < 2; i++)
#pragma unroll
                for (int j = 0; j < 2; j++) {
                    int gn = ns * BN + wc * 32 + j * 16 + fr;
                    float bv = bias[gn];
#pragma unroll
                    for (int r = 0; r < 4; r++) {
                        int gm = m0 + wr * 32 + i * 16 + orow + r;
                        float rv = (gm < M) ? res[(size_t)gm * 256 + gn] : 0.f;
                        float x = acc[ns][i][j][r] + bv + rv;
                        acc[ns][i][j][r] = x;
                        part[i][r] += x;
                    }
                }
#pragma unroll
        for (int i = 0; i < 2; i++)
#pragma unroll
            for (int r = 0; r < 4; r++) {
                float v = part[i][r];
                v += __shfl_xor(v, 1);
                v += __shfl_xor(v, 2);
                v += __shfl_xor(v, 4);
                v += __shfl_xor(v, 8);
                part[i][r] = v;
            }
        if (fr == 0) {
#pragma unroll
            for (int i = 0; i < 2; i++)
#pragma unroll
                for (int r = 0; r < 4; r++)
                    rsum[(wr * 32 + i * 16 + orow + r) * 2 + wc] = part[i][r];
        }
        __syncthreads();
        float mean[2][4];
#pragma unroll
        for (int i = 0; i < 2; i++)
#pragma unroll
            for (int r = 0; r < 4; r++) {
                int rl = wr * 32 + i * 16 + orow + r;
                mean[i][r] = (rsum[rl * 2] + rsum[rl * 2 + 1]) * (1.f / 256.f);
            }
        float p2[2][4] = {};
#pragma unroll
        for (int ns = 0; ns < NSUB; ns++)
#pragma unroll
            for (int i = 0; i < 2; i++)
#pragma unroll
                for (int j = 0; j < 2; j++)
#pragma unroll
                    for (int r = 0; r < 4; r++) {
                        float d = acc[ns][i][j][r] - mean[i][r];
                        p2[i][r] += d * d;
                    }
#pragma unroll
        for (int i = 0; i < 2; i++)
#pragma unroll
            for (int r = 0; r < 4; r++) {
                float v = p2[i][r];
                v += __shfl_xor(v, 1);
                v += __shfl_xor(v, 2);
                v += __shfl_xor(v, 4);
                v += __shfl_xor(v, 8);
                p2[i][r] = v;
            }
        if (fr == 0) {
#pragma unroll
            for (int i = 0; i < 2; i++)
#pragma unroll
                for (int r = 0; r < 4; r++)
                    rsum2[(wr * 32 + i * 16 + orow + r) * 2 + wc] = p2[i][r];
        }
        __syncthreads();
        float rstd[2][4];
#pragma unroll
        for (int i = 0; i < 2; i++)
#pragma unroll
            for (int r = 0; r < 4; r++) {
                int rl = wr * 32 + i * 16 + orow + r;
                float var = (rsum2[rl * 2] + rsum2[rl * 2 + 1]) * (1.f / 256.f);
                rstd[i][r] = rsqrtf(var + 1e-5f);
            }
#pragma unroll
        for (int ns = 0; ns < NSUB; ns++)
#pragma unroll
            for (int i = 0; i < 2; i++)
#pragma unroll
                for (int j = 0; j < 2; j++) {
                    int gn = ns * BN + wc * 32 + j * 16 + fr;
                    float gv = lng[gn], bev = lnb[gn];
#pragma unroll
                    for (int r = 0; r < 4; r++) {
                        int gm = m0 + wr * 32 + i * 16 + orow + r;
                        if (gm < M) {
                            float y = (acc[ns][i][j][r] - mean[i][r]) * rstd[i][r] * gv + bev;
                            stval(C + (size_t)gm * 256 + gn, y);
                        }
                    }
                }
    }
}

template <typename AT, typename OT, int RELU, int NSUB, bool LNF>
__global__ __launch_bounds__(256) void mfma_gemm(
    const AT* __restrict__ A, const float* __restrict__ A2,
    const __bf16* __restrict__ Wt,
    const float* __restrict__ bias, const float* __restrict__ bias2, int nsplit,
    const float* __restrict__ res, const float* __restrict__ lng,
    const float* __restrict__ lnb,
    OT* __restrict__ C, int M, int N, int K) {
    __shared__ __attribute__((aligned(16))) char lds[BM * BKK * 2 + NSUB * BN * BKK * 2 + (LNF ? 1024 : 0)];
    gemm_body<AT, OT, RELU, NSUB, LNF>(blockIdx.x, blockIdx.y, lds, A, A2, Wt,
                                       bias, bias2, nsplit, res, lng, lnb, C, M, N, K);
}

// ============ value body: dbuf + counted vmcnt, wave-private B ==============
__device__ __forceinline__ void value_body(
    int bx, char* ldsraw,
    const float* __restrict__ A, const __bf16* __restrict__ Wt,
    const float* __restrict__ bias, __bf16* __restrict__ C) {
    int tid = threadIdx.x;
    int lane = tid & 63;
    int wave = tid >> 6;
    int fr = lane & 15, gq = lane >> 4;
    int m0 = bx * 64;

    __bf16* As = (__bf16*)ldsraw;             // [2][64*64]  16 KB
    __bf16* Bq = (__bf16*)(ldsraw + 16384);   // [2][4][64*64] 64 KB

    f32x4 acc[4][4] = {};

    int srow = tid >> 2;
    int sq = tid & 3;
    int u0 = sq << 1;
    int p0 = (u0 ^ (srow & 7)) * 8;
    int p1 = ((u0 + 1) ^ (srow & 7)) * 8;

    int c_row = lane >> 3;
    int c_u = lane & 7;
    int gu = c_u ^ c_row;
    const __bf16* bsrc0 = Wt + (size_t)(wave * 64 + c_row) * 256 + gu * 8;
    const float* aptr = A + (size_t)(m0 + srow) * 256 + sq * 16;

    f32x4 fa0 = *(const f32x4*)(aptr + 0);
    f32x4 fa1 = *(const f32x4*)(aptr + 4);
    f32x4 fa2 = *(const f32x4*)(aptr + 8);
    f32x4 fa3 = *(const f32x4*)(aptr + 12);
    __builtin_amdgcn_sched_barrier(0);
#pragma unroll
    for (int c = 0; c < 8; c++)
        gload16(bsrc0 + (size_t)c * 8 * 256, &Bq[wave * 4096 + c * 512]);
    asm volatile("s_waitcnt vmcnt(8)" ::: "memory");
    __builtin_amdgcn_sched_barrier(0);
    {
        bf16x8 v0, v1;
#pragma unroll
        for (int e = 0; e < 4; e++) {
            v0[e] = (__bf16)fa0[e]; v0[e + 4] = (__bf16)fa1[e];
            v1[e] = (__bf16)fa2[e]; v1[e + 4] = (__bf16)fa3[e];
        }
        *(bf16x8*)(&As[srow * 64 + p0]) = v0;
        *(bf16x8*)(&As[srow * 64 + p1]) = v1;
    }
    asm volatile("s_waitcnt lgkmcnt(0)" ::: "memory");
    __builtin_amdgcn_s_barrier();

#pragma unroll
    for (int step = 0; step < 4; step++) {
        int p = step & 1;
        if (step < 3) {
            const float* ap2 = aptr + (step + 1) * 64;
            fa0 = *(const f32x4*)(ap2 + 0);
            fa1 = *(const f32x4*)(ap2 + 4);
            fa2 = *(const f32x4*)(ap2 + 8);
            fa3 = *(const f32x4*)(ap2 + 12);
            __builtin_amdgcn_sched_barrier(0);
            const __bf16* bsrc = bsrc0 + (step + 1) * 64;
#pragma unroll
            for (int c = 0; c < 8; c++)
                gload16(bsrc + (size_t)c * 8 * 256, &Bq[((p ^ 1) * 4 + wave) * 4096 + c * 512]);
            asm volatile("s_waitcnt vmcnt(12)" ::: "memory");
        } else {
            asm volatile("s_waitcnt vmcnt(0)" ::: "memory");
        }
        __builtin_amdgcn_sched_barrier(0);
#pragma unroll
        for (int ks = 0; ks < 2; ks++) {
            bf16x8 a[4], b[4];
#pragma unroll
            for (int i = 0; i < 4; i++) {
                int ma = i * 16 + fr;
                a[i] = *(const bf16x8*)(&As[p * 4096 + ma * 64 + ((ks * 4 + gq) ^ (ma & 7)) * 8]);
                b[i] = *(const bf16x8*)(&Bq[(p * 4 + wave) * 4096 + ma * 64 + ((ks * 4 + gq) ^ (ma & 7)) * 8]);
            }
#pragma unroll
            for (int i = 0; i < 4; i++)
#pragma unroll
                for (int j = 0; j < 4; j++)
                    acc[i][j] = __builtin_amdgcn_mfma_f32_16x16x32_bf16(a[i], b[j], acc[i][j], 0, 0, 0);
        }
        if (step < 3) {
            asm volatile("s_waitcnt vmcnt(8)" ::: "memory");
            __builtin_amdgcn_sched_barrier(0);
            bf16x8 v0, v1;
#pragma unroll
            for (int e = 0; e < 4; e++) {
                v0[e] = (__bf16)fa0[e]; v0[e + 4] = (__bf16)fa1[e];
                v1[e] = (__bf16)fa2[e]; v1[e + 4] = (__bf16)fa3[e];
            }
            *(bf16x8*)(&As[(p ^ 1) * 4096 + srow * 64 + p0]) = v0;
            *(bf16x8*)(&As[(p ^ 1) * 4096 + srow * 64 + p1]) = v1;
            asm volatile("s_waitcnt lgkmcnt(0)" ::: "memory");
            __builtin_amdgcn_s_barrier();
        }
    }

#pragma unroll
    for (int i = 0; i < 4; i++)
#pragma unroll
        for (int j = 0; j < 4; j++) {
            int gn = wave * 64 + j * 16 + fr;
            float bv = bias[gn];
#pragma unroll
            for (int r = 0; r < 4; r++) {
                int gm = m0 + i * 16 + gq * 4 + r;
                C[(size_t)gm * 256 + gn] = (__bf16)(acc[i][j][r] + bv);
            }
        }
}

// ============ fused head: value proj + QK proj + V proj in one launch =======
#define NVALB 1360
#define NQKB  228
#define NVB   228

__global__ __launch_bounds__(256) void fused_head(
    const float* __restrict__ input_flat, const __bf16* __restrict__ wt_val,
    const float* __restrict__ value_b, __bf16* __restrict__ vbig,
    const float* __restrict__ query, const float* __restrict__ query_pos,
    const __bf16* __restrict__ wt_q, const float* __restrict__ sa_in_b,
    __bf16* __restrict__ qkbuf, const __bf16* __restrict__ wt_v,
    __bf16* __restrict__ Vp, int M) {
    __shared__ __attribute__((aligned(16))) char lds[81920];
    int bx = blockIdx.x;
    if (bx < NVALB) {
        value_body(bx, lds, input_flat, wt_val, value_b, vbig);
    } else if (bx < NVALB + NQKB) {
        int b2 = bx - NVALB;
        gemm_body<float, __bf16, 0, 2, false>(b2 & 3, b2 >> 2, lds,
            query, query_pos, wt_q, sa_in_b, sa_in_b, 1 << 30,
            nullptr, nullptr, nullptr, qkbuf, M, 512, 256);
    } else {
        int b2 = bx - NVALB - NQKB;
        gemm_body<float, __bf16, 0, 1, false>(b2 & 3, b2 >> 2, lds,
            query, nullptr, wt_v, sa_in_b + 512, sa_in_b, 1 << 30,
            nullptr, nullptr, nullptr, Vp, M, 256, 256);
    }
}

__global__ void fillmark(float* o, int n, float v) {
    int i = blockIdx.x * blockDim.x + threadIdx.x;
    if (i < n) o[i] = v;
}

// ---------------- MFMA flash self-attention (QK packed, stride 512) ---------
#define QT 64
#define KT 64
#define NT ((NQQ + KT - 1) / KT)   // 15
#define QKLD 512

__global__ __launch_bounds__(256) void sa_attn_mfma(
    const __bf16* __restrict__ QK, const __bf16* __restrict__ V,
    float* __restrict__ O) {
    int blk = blockIdx.x;
    int tq = blk % NT;
    int bh = blk / NT;
    int h = bh % NH;
    int b = bh / NH;
    int tid = threadIdx.x;
    int lane = tid & 63;
    int wave = tid >> 6;
    int fr = lane & 15, gq = lane >> 4;
    int q0 = tq * QT;

    __shared__ __attribute__((aligned(16))) __bf16 Ks[KT][56];
    __shared__ __attribute__((aligned(16))) __bf16 Vt[HDIM][72];
    __shared__ __attribute__((aligned(16))) __bf16 Ps[4][16][72];

    int qrow = q0 + wave * 16 + fr;
    bf16x8 aq = {};
    if (qrow < NQQ)
        aq = *(const bf16x8*)(QK + ((size_t)(b * NQQ + qrow)) * QKLD + h * HDIM + gq * 8);

    f32x4 o0 = {}, o1 = {};
    float m_r[4] = {-1e30f, -1e30f, -1e30f, -1e30f};
    float l_r[4] = {0.f, 0.f, 0.f, 0.f};
    const float scale = 0.17677669529663687f;

    for (int kt = 0; kt < NT; kt++) {
        int kv0 = kt * KT;
        {
            int r = tid >> 2;
            int c8 = (tid & 3) * 8;
            int kvr = kv0 + r;
            bf16x8 kv_ = {}, vv_ = {};
            if (kvr < NQQ) {
                kv_ = *(const bf16x8*)(QK + ((size_t)(b * NQQ + kvr)) * QKLD + 256 + h * HDIM + c8);
                vv_ = *(const bf16x8*)(V + ((size_t)(b * NQQ + kvr)) * DD + h * HDIM + c8);
            }
            *(bf16x8*)(&Ks[r][c8]) = kv_;
#pragma unroll
            for (int j = 0; j < 8; j++) Vt[c8 + j][r] = vv_[j];
        }
        __syncthreads();

        f32x4 s[4];
#pragma unroll
        for (int f = 0; f < 4; f++) {
            bf16x8 bk = *(const bf16x8*)(&Ks[f * 16 + fr][gq * 8]);
            f32x4 z = {};
            s[f] = __builtin_amdgcn_mfma_f32_16x16x32_bf16(aq, bk, z, 0, 0, 0);
        }
#pragma unroll
        for (int f = 0; f < 4; f++) {
            bool valid = (kv0 + f * 16 + fr) < NQQ;
#pragma unroll
            for (int r = 0; r < 4; r++)
                s[f][r] = valid ? s[f][r] * scale : -1e30f;
        }
        float sc_[4];
#pragma unroll
        for (int r = 0; r < 4; r++) {
            float v = fmaxf(fmaxf(s[0][r], s[1][r]), fmaxf(s[2][r], s[3][r]));
            v = fmaxf(v, __shfl_xor(v, 1));
            v = fmaxf(v, __shfl_xor(v, 2));
            v = fmaxf(v, __shfl_xor(v, 4));
            v = fmaxf(v, __shfl_xor(v, 8));
            float mn = fmaxf(m_r[r], v);
            sc_[r] = expf(m_r[r] - mn);
            m_r[r] = mn;
        }
        float rs[4] = {0.f, 0.f, 0.f, 0.f};
#pragma unroll
        for (int f = 0; f < 4; f++)
#pragma unroll
            for (int r = 0; r < 4; r++) {
                float e = expf(s[f][r] - m_r[r]);
                s[f][r] = e;
                rs[r] += e;
            }
#pragma unroll
        for (int r = 0; r < 4; r++) {
            float v = rs[r];
            v += __shfl_xor(v, 1);
            v += __shfl_xor(v, 2);
            v += __shfl_xor(v, 4);
            v += __shfl_xor(v, 8);
            l_r[r] = l_r[r] * sc_[r] + v;
            o0[r] *= sc_[r];
            o1[r] *= sc_[r];
        }
#pragma unroll
        for (int f = 0; f < 4; f++)
#pragma unroll
            for (int r = 0; r < 4; r++)
                Ps[wave][gq * 4 + r][f * 16 + fr] = (__bf16)s[f][r];
#pragma unroll
        for (int c = 0; c < 2; c++) {
            bf16x8 ap = *(const bf16x8*)(&Ps[wave][fr][c * 32 + gq * 8]);
            bf16x8 bv0 = *(const bf16x8*)(&Vt[fr][c * 32 + gq * 8]);
            bf16x8 bv1 = *(const bf16x8*)(&Vt[16 + fr][c * 32 + gq * 8]);
            o0 = __builtin_amdgcn_mfma_f32_16x16x32_bf16(ap, bv0, o0, 0, 0, 0);
            o1 = __builtin_amdgcn_mfma_f32_16x16x32_bf16(ap, bv1, o1, 0, 0, 0);
        }
        __syncthreads();
    }
#pragma unroll
    for (int r = 0; r < 4; r++) {
        int qr = q0 + wave * 16 + gq * 4 + r;
        if (qr < NQQ) {
            float inv = 1.f / l_r[r];
            O[((size_t)(b * NQQ + qr)) * DD + h * HDIM + fr] = o0[r] * inv;
            O[((size_t)(b * NQQ + qr)) * DD + h * HDIM + 16 + fr] = o1[r] * inv;
        }
    }
}

// ---------------- msdeform v3: 1 query/block, 16B gathers, shfl reduce -------
#define OAW 384

__global__ __launch_bounds__(256) void msdeform3(
    const __bf16* __restrict__ val, const __bf16* __restrict__ oa,
    const float* __restrict__ ref, float* __restrict__ out) {
    int tid = threadIdx.x;
    int row = blockIdx.x;               // flat b*NQQ+q
    int b_ = row / NQQ;

    __shared__ float sx[128], sy[128], sw[128];

    if (tid < 128) {
        int h = tid >> 4;
        int lp = tid & 15;
        int l = lp >> 2;
        float logit = (float)oa[(size_t)row * OAW + 256 + h * 16 + lp];
        float ox = (float)oa[(size_t)row * OAW + h * 32 + lp * 2];
        float oy = (float)oa[(size_t)row * OAW + h * 32 + lp * 2 + 1];
        const float* rp = ref + ((size_t)row * LV + l) * 4;
        float cx = rp[0], cy = rp[1], rw = rp[2], rh = rp[3];
        float mv = logit;
        mv = fmaxf(mv, __shfl_xor(mv, 1));
        mv = fmaxf(mv, __shfl_xor(mv, 2));
        mv = fmaxf(mv, __shfl_xor(mv, 4));
        mv = fmaxf(mv, __shfl_xor(mv, 8));
        float e = expf(logit - mv);
        float sum = e;
        sum += __shfl_xor(sum, 1);
        sum += __shfl_xor(sum, 2);
        sum += __shfl_xor(sum, 4);
        sum += __shfl_xor(sum, 8);
        int Wl = 128 >> l;
        float lx = cx + ox * (1.0f / NP) * rw * 0.5f;
        float ly = cy + oy * (1.0f / NP) * rh * 0.5f;
        sx[tid] = lx * Wl - 0.5f;
        sy[tid] = ly * Wl - 0.5f;       // H == W for all levels
        sw[tid] = e / sum;
    }
    __syncthreads();

    int cpar = tid & 7;
    int dgrp = (tid >> 3) & 3;
    int h = tid >> 5;
    const int stt[4] = {0, 16384, 20480, 21504};
    const __bf16* vb = val + (size_t)b_ * SS * DD + h * HDIM + dgrp * 8;
    float facc[8] = {};
#pragma unroll
    for (int k = 0; k < 8; k++) {
        int combo = cpar * 8 + k;       // 0..63 unique per (lp,tap)
        int lp = combo >> 2;
        int tap = combo & 3;
        int l = lp >> 2;
        int Wl = 128 >> l;
        int cidx = h * 16 + lp;
        float x = sx[cidx], y = sy[cidx], w = sw[cidx];
        float x0f = floorf(x), y0f = floorf(y);
        float dx = x - x0f, dy = y - y0f;
        int xi = (int)x0f + (tap & 1);
        int yi = (int)y0f + (tap >> 1);
        float wt = ((tap & 1) ? dx : 1.f - dx) * ((tap >> 1) ? dy : 1.f - dy) * w;
        if ((xi >= 0) & (xi < Wl) & (yi >= 0) & (yi < Wl)) {
            bf16x8 t = *(const bf16x8*)(vb + (size_t)(stt[l] + yi * Wl + xi) * DD);
#pragma unroll
            for (int e = 0; e < 8; e++) facc[e] += wt * (float)t[e];
        }
    }
#pragma unroll
    for (int e = 0; e < 8; e++) {
        facc[e] += __shfl_xor(facc[e], 1);
        facc[e] += __shfl_xor(facc[e], 2);
        facc[e] += __shfl_xor(facc[e], 4);
    }
    float v = facc[0];
#pragma unroll
    for (int e = 1; e < 8; e++) if (cpar == e) v = facc[e];
    out[(size_t)row * DD + tid] = v;
}

// ---------------- launch ----------------
extern "C" void kernel_launch(void* const* d_in, const int* in_sizes, int n_in,
                              void* d_out, int out_size, void* d_ws, size_t ws_size,
                              hipStream_t stream) {
    const float* query      = (const float*)d_in[0];
    const float* query_pos  = (const float*)d_in[1];
    const float* refpts     = (const float*)d_in[2];
    const float* input_flat = (const float*)d_in[3];
    const float* sa_in_w    = (const float*)d_in[6];
    const float* sa_in_b    = (const float*)d_in[7];
    const float* sa_out_w   = (const float*)d_in[8];
    const float* sa_out_b   = (const float*)d_in[9];
    const float* norm1_g    = (const float*)d_in[10];
    const float* norm1_b    = (const float*)d_in[11];
    const float* value_w    = (const float*)d_in[12];
    const float* value_b    = (const float*)d_in[13];
    const float* off_w      = (const float*)d_in[14];
    const float* off_b      = (const float*)d_in[15];
    const float* aw_w       = (const float*)d_in[16];
    const float* aw_b       = (const float*)d_in[17];
    const float* ca_out_w   = (const float*)d_in[18];
    const float* ca_out_b   = (const float*)d_in[19];
    const float* norm2_g    = (const float*)d_in[20];
    const float* norm2_b    = (const float*)d_in[21];
    const float* lin1_w     = (const float*)d_in[22];
    const float* lin1_b     = (const float*)d_in[23];
    const float* lin2_w     = (const float*)d_in[24];
    const float* lin2_b     = (const float*)d_in[25];
    const float* norm3_g    = (const float*)d_in[26];
    const float* norm3_b    = (const float*)d_in[27];
    float* out = (float*)d_out;

    const int M = BB * NQQ;              // 3600
    const int NE = M * DD;               // 921600
    const size_t slotBytes = (size_t)NE * 4;
    const size_t wElems = 6 * 65536 + 32768 + 65536 + 2 * 524288;
    const size_t wBytes = wElems * 2;
    const size_t bigBytes = (size_t)BB * SS * DD * 2;
    const size_t needBytes = 3 * slotBytes + wBytes + bigBytes;
    if (ws_size < needBytes) {
        float mark = 1000.0f + (float)(ws_size >> 20);
        fillmark<<<(out_size + 255) / 256, 256, 0, stream>>>(out, out_size, mark);
        return;
    }

    char* wsb = (char*)d_ws;
    float* s0 = (float*)(wsb);
    float* s1 = (float*)(wsb + slotBytes);
    float* s2 = (float*)(wsb + 2 * slotBytes);
    __bf16* wb = (__bf16*)(wsb + 3 * slotBytes);
    __bf16* vbig = (__bf16*)(wsb + 3 * slotBytes + wBytes);

    __bf16* wt_q   = wb;                 // [512][256] combined with wt_k
    __bf16* wt_k   = wb + 65536;
    __bf16* wt_v   = wb + 131072;
    __bf16* wt_sa  = wb + 196608;
    __bf16* wt_val = wb + 262144;
    __bf16* wt_off = wb + 327680;        // [384][256] combined with wt_aw
    __bf16* wt_aw  = wb + 393216;
    __bf16* wt_ca  = wb + 425984;
    __bf16* wt_l1  = wb + 491520;
    __bf16* wt_l2  = wb + 1015808;

    TPtrs tp;
    tp.s[0] = sa_in_w;          tp.d[0] = wt_q;
    tp.s[1] = sa_in_w + 65536;  tp.d[1] = wt_k;
    tp.s[2] = sa_in_w + 131072; tp.d[2] = wt_v;
    tp.s[3] = sa_out_w;         tp.d[3] = wt_sa;
    tp.s[4] = value_w;          tp.d[4] = wt_val;
    tp.s[5] = off_w;            tp.d[5] = wt_off;
    tp.s[6] = aw_w;             tp.d[6] = wt_aw;
    tp.s[7] = ca_out_w;         tp.d[7] = wt_ca;
    tp.s[8] = lin1_w;           tp.d[8] = wt_l1;
    tp.s[9] = lin2_w;           tp.d[9] = wt_l2;
    transp_all<<<1504, dim3(32, 8), 0, stream>>>(tp);

    __bf16* qkbuf = (__bf16*)s1;     // [M][512]
    __bf16* Vp = (__bf16*)s2;        // [M][256]
    __bf16* oabuf = (__bf16*)s1;     // [M][384] (after attn, qk dead)

    const int mt = (M + BM - 1) / BM;    // 57
    const int BIG = 1 << 30;

    // fused: value proj + QK proj(+query_pos) + V proj in one launch
    fused_head<<<NVALB + NQKB + NVB, 256, 0, stream>>>(
        input_flat, wt_val, value_b, vbig,
        query, query_pos, wt_q, sa_in_b, qkbuf, wt_v, Vp, M);
    // attention -> s0 (own kernel, small LDS => high occupancy)
    sa_attn_mfma<<<BB * NH * NT, 256, 0, stream>>>(qkbuf, Vp, s0);
    // sa projection + residual(query) + LN1 fused -> s2 (x1)
    mfma_gemm<float, float, 0, 4, true><<<dim3(1, mt), 256, 0, stream>>>(
        s0, nullptr, wt_sa, sa_out_b, sa_out_b, BIG,
        query, norm1_g, norm1_b, s2, M, DD, DD);
    // off+aw projection (fused +query_pos), N=384 -> s1
    mfma_gemm<float, __bf16, 0, 1, false><<<dim3(6, mt), 256, 0, stream>>>(
        s2, query_pos, wt_off, off_b, aw_b, 256,
        nullptr, nullptr, nullptr, oabuf, M, OAW, DD);
    // deformable sampling -> s0
    msdeform3<<<M, 256, 0, stream>>>(vbig, oabuf, refpts, s0);
    // ca projection + residual(x1) + LN2 fused -> s1 (x2)
    mfma_gemm<float, float, 0, 4, true><<<dim3(1, mt), 256, 0, stream>>>(
        s0, nullptr, wt_ca, ca_out_b, ca_out_b, BIG,
        s2, norm2_g, norm2_b, s1, M, DD, DD);
    // ffn1 -> vbig (bf16, relu), NSUB=2
    mfma_gemm<float, __bf16, 1, 2, false><<<dim3(16, mt), 256, 0, stream>>>(
        s1, nullptr, wt_l1, lin1_b, lin1_b, BIG,
        nullptr, nullptr, nullptr, vbig, M, DFF, DD);
    // ffn2 + residual(x2) + LN3 fused -> d_out
    mfma_gemm<__bf16, float, 0, 4, true><<<dim3(1, mt), 256, 0, stream>>>(
        vbig, nullptr, wt_l2, lin2_b, lin2_b, BIG,
        s1, norm3_g, norm3_b, out, M, DD, DFF);
}

// Round 17
// 203.739 us; speedup vs baseline: 1.0849x; 1.0849x over previous
//
#include <hip/hip_runtime.h>
#include <hip/hip_bf16.h>

#define DD   256
#define NH   8
#define HDIM 32
#define LV   4
#define NP   4
#define DFF  2048
#define BB   4
#define NQQ  900
#define SS   21760

typedef __bf16 bf16x8 __attribute__((ext_vector_type(8)));
typedef __bf16 bf16x2 __attribute__((ext_vector_type(2)));
typedef float  f32x4  __attribute__((ext_vector_type(4)));

__device__ inline void stval(float* p, float v) { *p = v; }
__device__ inline void stval(__bf16* p, float v) { *p = (__bf16)v; }

__device__ __forceinline__ void gload16(const void* g, void* l) {
    __builtin_amdgcn_global_load_lds(
        (const __attribute__((address_space(1))) void*)g,
        (__attribute__((address_space(3))) void*)l, 16, 0, 0);
}

// ============ all weight transposes in ONE launch ============================
struct TPtrs {
    const float* s[10];
    __bf16* d[10];
};

__global__ void transp_all(TPtrs P) {
    const int Ks[10] = {256, 256, 256, 256, 256, 256, 256, 256, 256, 2048};
    const int Ns[10] = {256, 256, 256, 256, 256, 256, 128, 256, 2048, 256};
    const int tiles[10] = {64, 64, 64, 64, 64, 64, 32, 64, 512, 512};
    int t = blockIdx.x;
    int j = 0, base = 0;
    while (t >= base + tiles[j]) { base += tiles[j]; j++; }
    int lt = t - base;
    int K = Ks[j], N = Ns[j];
    int tn = N >> 5;
    int nb = (lt % tn) * 32, kb = (lt / tn) * 32;
    const float* W = P.s[j];
    __bf16* Wt = P.d[j];
    __shared__ float tbuf[32][33];
    for (int i = threadIdx.y; i < 32; i += 8)
        tbuf[i][threadIdx.x] = W[(size_t)(kb + i) * N + nb + threadIdx.x];
    __syncthreads();
    for (int i = threadIdx.y; i < 32; i += 8)
        Wt[(size_t)(nb + i) * K + kb + threadIdx.x] = (__bf16)tbuf[threadIdx.x][i];
}

// ============ GEMM body (device fn): C = (A[+A2]) @ Wt^T + bias [opt LN] ====
#define BM 64
#define BN 64
#define BKK 64

template <typename AT, typename OT, int RELU, int NSUB, bool LNF>
__device__ __forceinline__ void gemm_body(
    int bx, int by, char* ldsraw,
    const AT* __restrict__ A, const float* __restrict__ A2,
    const __bf16* __restrict__ Wt,
    const float* __restrict__ bias, const float* __restrict__ bias2, int nsplit,
    const float* __restrict__ res, const float* __restrict__ lng,
    const float* __restrict__ lnb,
    OT* __restrict__ C, int M, int N, int K) {
    int tid = threadIdx.x;
    int lane = tid & 63;
    int wave = tid >> 6;
    int wr = wave >> 1, wc = wave & 1;
    int m0 = by * BM;
    int n0 = bx * (BN * NSUB);

    __bf16* As = (__bf16*)ldsraw;
    __bf16* Bs = (__bf16*)(ldsraw + BM * BKK * 2);
    float* rsum  = (float*)(ldsraw + BM * BKK * 2 + NSUB * BN * BKK * 2);
    float* rsum2 = rsum + 128;

    f32x4 acc[NSUB][2][2] = {};

    int srow = tid >> 2;
    int sq = tid & 3;
    int u0 = sq << 1;
    int p0 = (u0 ^ (srow & 7)) * 8;
    int p1 = ((u0 + 1) ^ (srow & 7)) * 8;
    int fr = lane & 15, gq = lane >> 4;

    for (int k0 = 0; k0 < K; k0 += BKK) {
        {
            int gm = m0 + srow;
            bf16x8 v0 = {}, v1 = {};
            if (gm < M) {
                if constexpr (sizeof(AT) == 4) {
                    const float* ap = (const float*)A + (size_t)gm * K + k0 + sq * 16;
                    f32x4 f0 = *(const f32x4*)(ap + 0);
                    f32x4 f1 = *(const f32x4*)(ap + 4);
                    f32x4 f2 = *(const f32x4*)(ap + 8);
                    f32x4 f3 = *(const f32x4*)(ap + 12);
                    if (A2) {
                        const float* ap2 = A2 + (size_t)gm * K + k0 + sq * 16;
                        f0 += *(const f32x4*)(ap2 + 0);
                        f1 += *(const f32x4*)(ap2 + 4);
                        f2 += *(const f32x4*)(ap2 + 8);
                        f3 += *(const f32x4*)(ap2 + 12);
                    }
#pragma unroll
                    for (int e = 0; e < 4; e++) {
                        v0[e] = (__bf16)f0[e]; v0[e + 4] = (__bf16)f1[e];
                        v1[e] = (__bf16)f2[e]; v1[e + 4] = (__bf16)f3[e];
                    }
                } else {
                    const __bf16* ap = (const __bf16*)A + (size_t)gm * K + k0 + sq * 16;
                    v0 = *(const bf16x8*)(ap);
                    v1 = *(const bf16x8*)(ap + 8);
                }
            }
            *(bf16x8*)(&As[srow * 64 + p0]) = v0;
            *(bf16x8*)(&As[srow * 64 + p1]) = v1;
        }
#pragma unroll
        for (int ns = 0; ns < NSUB; ns++) {
            int gn = n0 + ns * BN + srow;
            const __bf16* bp = Wt + (size_t)gn * K + k0 + sq * 16;
            bf16x8 w0 = *(const bf16x8*)(bp);
            bf16x8 w1 = *(const bf16x8*)(bp + 8);
            *(bf16x8*)(&Bs[ns * BN * BKK + srow * 64 + p0]) = w0;
            *(bf16x8*)(&Bs[ns * BN * BKK + srow * 64 + p1]) = w1;
        }
        __syncthreads();
#pragma unroll
        for (int ks = 0; ks < 2; ks++) {
            bf16x8 a[2];
#pragma unroll
            for (int i = 0; i < 2; i++) {
                int ma = wr * 32 + i * 16 + fr;
                a[i] = *(const bf16x8*)(&As[ma * 64 + ((ks * 4 + gq) ^ (ma & 7)) * 8]);
            }
#pragma unroll
            for (int ns = 0; ns < NSUB; ns++) {
                bf16x8 b[2];
#pragma unroll
                for (int j = 0; j < 2; j++) {
                    int nb = wc * 32 + j * 16 + fr;
                    b[j] = *(const bf16x8*)(&Bs[ns * BN * BKK + nb * 64 + ((ks * 4 + gq) ^ (nb & 7)) * 8]);
                }
#pragma unroll
                for (int i = 0; i < 2; i++)
#pragma unroll
                    for (int j = 0; j < 2; j++)
                        acc[ns][i][j] = __builtin_amdgcn_mfma_f32_16x16x32_bf16(a[i], b[j], acc[ns][i][j], 0, 0, 0);
            }
        }
        __syncthreads();
    }
    int orow = gq * 4;
    if constexpr (!LNF) {
#pragma unroll
        for (int ns = 0; ns < NSUB; ns++)
#pragma unroll
            for (int i = 0; i < 2; i++)
#pragma unroll
                for (int j = 0; j < 2; j++) {
                    int gn = n0 + ns * BN + wc * 32 + j * 16 + fr;
                    float bv = (gn < nsplit) ? bias[gn] : bias2[gn - nsplit];
#pragma unroll
                    for (int r = 0; r < 4; r++) {
                        int gm = m0 + wr * 32 + i * 16 + orow + r;
                        if (gm < M) {
                            float v = acc[ns][i][j][r] + bv;
                            if (RELU) v = fmaxf(v, 0.f);
                            stval(C + (size_t)gm * N + gn, v);
                        }
                    }
                }
    } else {
        float part[2][4] = {};
#pragma unroll
        for (int ns = 0; ns < NSUB; ns++)
#pragma unroll
            for (int i = 0; i < 2; i++)
#pragma unroll
                for (int j = 0; j < 2; j++) {
                    int gn = ns * BN + wc * 32 + j * 16 + fr;
                    float bv = bias[gn];
#pragma unroll
                    for (int r = 0; r < 4; r++) {
                        int gm = m0 + wr * 32 + i * 16 + orow + r;
                        float rv = (gm < M) ? res[(size_t)gm * 256 + gn] : 0.f;
                        float x = acc[ns][i][j][r] + bv + rv;
                        acc[ns][i][j][r] = x;
                        part[i][r] += x;
                    }
                }
#pragma unroll
        for (int i = 0; i < 2; i++)
#pragma unroll
            for (int r = 0; r < 4; r++) {
                float v = part[i][r];
                v += __shfl_xor(v, 1);
                v += __shfl_xor(v, 2);
                v += __shfl_xor(v, 4);
                v += __shfl_xor(v, 8);
                part[i][r] = v;
            }
        if (fr == 0) {
#pragma unroll
            for (int i = 0; i < 2; i++)
#pragma unroll
                for (int r = 0; r < 4; r++)
                    rsum[(wr * 32 + i * 16 + orow + r) * 2 + wc] = part[i][r];
        }
        __syncthreads();
        float mean[2][4];
#pragma unroll
        for (int i = 0; i < 2; i++)
#pragma unroll
            for (int r = 0; r < 4; r++) {
                int rl = wr * 32 + i * 16 + orow + r;
                mean[i][r] = (rsum[rl * 2] + rsum[rl * 2 + 1]) * (1.f / 256.f);
            }
        float p2[2][4] = {};
#pragma unroll
        for (int ns = 0; ns < NSUB; ns++)
#pragma unroll
            for (int i = 0; i < 2; i++)
#pragma unroll
                for (int j = 0; j < 2; j++)
#pragma unroll
                    for (int r = 0; r < 4; r++) {
                        float d = acc[ns][i][j][r] - mean[i][r];
                        p2[i][r] += d * d;
                    }
#pragma unroll
        for (int i = 0; i < 2; i++)
#pragma unroll
            for (int r = 0; r < 4; r++) {
                float v = p2[i][r];
                v += __shfl_xor(v, 1);
                v += __shfl_xor(v, 2);
                v += __shfl_xor(v, 4);
                v += __shfl_xor(v, 8);
                p2[i][r] = v;
            }
        if (fr == 0) {
#pragma unroll
            for (int i = 0; i < 2; i++)
#pragma unroll
                for (int r = 0; r < 4; r++)
                    rsum2[(wr * 32 + i * 16 + orow + r) * 2 + wc] = p2[i][r];
        }
        __syncthreads();
        float rstd[2][4];
#pragma unroll
        for (int i = 0; i < 2; i++)
#pragma unroll
            for (int r = 0; r < 4; r++) {
                int rl = wr * 32 + i * 16 + orow + r;
                float var = (rsum2[rl * 2] + rsum2[rl * 2 + 1]) * (1.f / 256.f);
                rstd[i][r] = rsqrtf(var + 1e-5f);
            }
#pragma unroll
        for (int ns = 0; ns < NSUB; ns++)
#pragma unroll
            for (int i = 0; i < 2; i++)
#pragma unroll
                for (int j = 0; j < 2; j++) {
                    int gn = ns * BN + wc * 32 + j * 16 + fr;
                    float gv = lng[gn], bev = lnb[gn];
#pragma unroll
                    for (int r = 0; r < 4; r++) {
                        int gm = m0 + wr * 32 + i * 16 + orow + r;
                        if (gm < M) {
                            float y = (acc[ns][i][j][r] - mean[i][r]) * rstd[i][r] * gv + bev;
                            stval(C + (size_t)gm * 256 + gn, y);
                        }
                    }
                }
    }
}

template <typename AT, typename OT, int RELU, int NSUB, bool LNF>
__global__ __launch_bounds__(256) void mfma_gemm(
    const AT* __restrict__ A, const float* __restrict__ A2,
    const __bf16* __restrict__ Wt,
    const float* __restrict__ bias, const float* __restrict__ bias2, int nsplit,
    const float* __restrict__ res, const float* __restrict__ lng,
    const float* __restrict__ lnb,
    OT* __restrict__ C, int M, int N, int K) {
    __shared__ __attribute__((aligned(16))) char lds[BM * BKK * 2 + NSUB * BN * BKK * 2 + (LNF ? 1024 : 0)];
    gemm_body<AT, OT, RELU, NSUB, LNF>(blockIdx.x, blockIdx.y, lds, A, A2, Wt,
                                       bias, bias2, nsplit, res, lng, lnb, C, M, N, K);
}

// ============ value body v5: 2-deep A prefetch + counted vmcnt ==============
// wave-private B dbuf (own vmcnt); A issued TWO steps ahead to cover HBM lat.
__device__ __forceinline__ void value_body(
    int bx, char* ldsraw,
    const float* __restrict__ A, const __bf16* __restrict__ Wt,
    const float* __restrict__ bias, __bf16* __restrict__ C) {
    int tid = threadIdx.x;
    int lane = tid & 63;
    int wave = tid >> 6;
    int fr = lane & 15, gq = lane >> 4;
    int m0 = bx * 64;

    __bf16* As = (__bf16*)ldsraw;             // [2][64*64]  16 KB
    __bf16* Bq = (__bf16*)(ldsraw + 16384);   // [2][4][64*64] 64 KB

    f32x4 acc[4][4] = {};

    int srow = tid >> 2;
    int sq = tid & 3;
    int u0 = sq << 1;
    int p0 = (u0 ^ (srow & 7)) * 8;
    int p1 = ((u0 + 1) ^ (srow & 7)) * 8;

    int c_row = lane >> 3;
    int c_u = lane & 7;
    int gu = c_u ^ c_row;
    const __bf16* bsrc0 = Wt + (size_t)(wave * 64 + c_row) * 256 + gu * 8;
    const float* aptr = A + (size_t)(m0 + srow) * 256 + sq * 16;

    f32x4 fA0, fA1, fA2, fA3;   // A prefetch set A
    f32x4 fB0, fB1, fB2, fB3;   // A prefetch set B

#define LOADA(s0_, s1_, s2_, s3_, off)                          \
    { const float* _p = aptr + (off);                           \
      s0_ = *(const f32x4*)(_p + 0);  s1_ = *(const f32x4*)(_p + 4); \
      s2_ = *(const f32x4*)(_p + 8);  s3_ = *(const f32x4*)(_p + 12); }

#define WRITEA(buf, s0_, s1_, s2_, s3_)                         \
    { bf16x8 _v0, _v1;                                          \
      _Pragma("unroll")                                         \
      for (int e = 0; e < 4; e++) {                             \
          _v0[e] = (__bf16)s0_[e]; _v0[e + 4] = (__bf16)s1_[e]; \
          _v1[e] = (__bf16)s2_[e]; _v1[e + 4] = (__bf16)s3_[e]; \
      }                                                         \
      *(bf16x8*)(&As[(buf) * 4096 + srow * 64 + p0]) = _v0;     \
      *(bf16x8*)(&As[(buf) * 4096 + srow * 64 + p1]) = _v1; }

#define ISSUEB(step, buf)                                       \
    { const __bf16* _b = bsrc0 + (step) * 64;                   \
      _Pragma("unroll")                                         \
      for (int c = 0; c < 8; c++)                               \
          gload16(_b + (size_t)c * 8 * 256, &Bq[((buf) * 4 + wave) * 4096 + c * 512]); }

#define MFMAS(buf)                                              \
    _Pragma("unroll")                                           \
    for (int ks = 0; ks < 2; ks++) {                            \
        bf16x8 a[4], b[4];                                      \
        _Pragma("unroll")                                       \
        for (int i = 0; i < 4; i++) {                           \
            int ma = i * 16 + fr;                               \
            a[i] = *(const bf16x8*)(&As[(buf) * 4096 + ma * 64 + ((ks * 4 + gq) ^ (ma & 7)) * 8]); \
            b[i] = *(const bf16x8*)(&Bq[((buf) * 4 + wave) * 4096 + ma * 64 + ((ks * 4 + gq) ^ (ma & 7)) * 8]); \
        }                                                       \
        _Pragma("unroll")                                       \
        for (int i = 0; i < 4; i++)                             \
            _Pragma("unroll")                                   \
            for (int j = 0; j < 4; j++)                         \
                acc[i][j] = __builtin_amdgcn_mfma_f32_16x16x32_bf16(a[i], b[j], acc[i][j], 0, 0, 0); \
    }

    // ---- prologue: A0, B0, A1 in flight; write A0 ----
    LOADA(fA0, fA1, fA2, fA3, 0);
    __builtin_amdgcn_sched_barrier(0);
    ISSUEB(0, 0);
    LOADA(fB0, fB1, fB2, fB3, 64);
    asm volatile("s_waitcnt vmcnt(12)" ::: "memory");   // A0 done (B0,A1 fly)
    __builtin_amdgcn_sched_barrier(0);
    WRITEA(0, fA0, fA1, fA2, fA3);
    asm volatile("s_waitcnt lgkmcnt(0)" ::: "memory");
    __builtin_amdgcn_s_barrier();

    // ---- step 0 (buf 0): prefetch B1, A2 ----
    ISSUEB(1, 1);
    LOADA(fA0, fA1, fA2, fA3, 128);
    asm volatile("s_waitcnt vmcnt(16)" ::: "memory");   // B0 done
    __builtin_amdgcn_sched_barrier(0);
    MFMAS(0);
    asm volatile("s_waitcnt vmcnt(12)" ::: "memory");   // A1 regs ready
    __builtin_amdgcn_sched_barrier(0);
    WRITEA(1, fB0, fB1, fB2, fB3);
    asm volatile("s_waitcnt lgkmcnt(0)" ::: "memory");
    __builtin_amdgcn_s_barrier();

    // ---- step 1 (buf 1): prefetch B2, A3 ----
    ISSUEB(2, 0);
    LOADA(fB0, fB1, fB2, fB3, 192);
    asm volatile("s_waitcnt vmcnt(16)" ::: "memory");   // B1 done
    __builtin_amdgcn_sched_barrier(0);
    MFMAS(1);
    asm volatile("s_waitcnt vmcnt(12)" ::: "memory");   // A2 regs ready
    __builtin_amdgcn_sched_barrier(0);
    WRITEA(0, fA0, fA1, fA2, fA3);
    asm volatile("s_waitcnt lgkmcnt(0)" ::: "memory");
    __builtin_amdgcn_s_barrier();

    // ---- step 2 (buf 0): prefetch B3 ----
    ISSUEB(3, 1);
    asm volatile("s_waitcnt vmcnt(12)" ::: "memory");   // B2 done
    __builtin_amdgcn_sched_barrier(0);
    MFMAS(0);
    asm volatile("s_waitcnt vmcnt(8)" ::: "memory");    // A3 regs ready
    __builtin_amdgcn_sched_barrier(0);
    WRITEA(1, fB0, fB1, fB2, fB3);
    asm volatile("s_waitcnt lgkmcnt(0)" ::: "memory");
    __builtin_amdgcn_s_barrier();

    // ---- step 3 (buf 1) ----
    asm volatile("s_waitcnt vmcnt(0)" ::: "memory");    // B3 done
    __builtin_amdgcn_sched_barrier(0);
    MFMAS(1);

#undef LOADA
#undef WRITEA
#undef ISSUEB
#undef MFMAS

#pragma unroll
    for (int i = 0; i < 4; i++)
#pragma unroll
        for (int j = 0; j < 4; j++) {
            int gn = wave * 64 + j * 16 + fr;
            float bv = bias[gn];
#pragma unroll
            for (int r = 0; r < 4; r++) {
                int gm = m0 + i * 16 + gq * 4 + r;
                C[(size_t)gm * 256 + gn] = (__bf16)(acc[i][j][r] + bv);
            }
        }
}

// ============ fused head: value proj + QK proj + V proj in one launch =======
#define NVALB 1360
#define NQKB  228
#define NVB   228

__global__ __launch_bounds__(256) void fused_head(
    const float* __restrict__ input_flat, const __bf16* __restrict__ wt_val,
    const float* __restrict__ value_b, __bf16* __restrict__ vbig,
    const float* __restrict__ query, const float* __restrict__ query_pos,
    const __bf16* __restrict__ wt_q, const float* __restrict__ sa_in_b,
    __bf16* __restrict__ qkbuf, const __bf16* __restrict__ wt_v,
    __bf16* __restrict__ Vp, int M) {
    __shared__ __attribute__((aligned(16))) char lds[81920];
    int bx = blockIdx.x;
    if (bx < NVALB) {
        value_body(bx, lds, input_flat, wt_val, value_b, vbig);
    } else if (bx < NVALB + NQKB) {
        int b2 = bx - NVALB;
        gemm_body<float, __bf16, 0, 2, false>(b2 & 3, b2 >> 2, lds,
            query, query_pos, wt_q, sa_in_b, sa_in_b, 1 << 30,
            nullptr, nullptr, nullptr, qkbuf, M, 512, 256);
    } else {
        int b2 = bx - NVALB - NQKB;
        gemm_body<float, __bf16, 0, 1, false>(b2 & 3, b2 >> 2, lds,
            query, nullptr, wt_v, sa_in_b + 512, sa_in_b, 1 << 30,
            nullptr, nullptr, nullptr, Vp, M, 256, 256);
    }
}

__global__ void fillmark(float* o, int n, float v) {
    int i = blockIdx.x * blockDim.x + threadIdx.x;
    if (i < n) o[i] = v;
}

// ---------------- residual + layernorm (LN3) ----------------
__global__ void ln_res(const float* a, const float* b,
                       const float* g, const float* be, float* o) {
    int row = blockIdx.x;
    int t = threadIdx.x;
    float x = a[(size_t)row * DD + t] + b[(size_t)row * DD + t];
    __shared__ float red[DD];
    red[t] = x;
    __syncthreads();
    for (int s = 128; s > 0; s >>= 1) {
        if (t < s) red[t] += red[t + s];
        __syncthreads();
    }
    float m = red[0] * (1.f / DD);
    __syncthreads();
    float d0 = x - m;
    red[t] = d0 * d0;
    __syncthreads();
    for (int s = 128; s > 0; s >>= 1) {
        if (t < s) red[t] += red[t + s];
        __syncthreads();
    }
    float v = red[0] * (1.f / DD);
    o[(size_t)row * DD + t] = d0 * rsqrtf(v + 1e-5f) * g[t] + be[t];
}

// ---------------- MFMA flash self-attention (QK packed, stride 512) ---------
#define QT 64
#define KT 64
#define NT ((NQQ + KT - 1) / KT)   // 15
#define QKLD 512

__global__ __launch_bounds__(256) void sa_attn_mfma(
    const __bf16* __restrict__ QK, const __bf16* __restrict__ V,
    float* __restrict__ O) {
    int blk = blockIdx.x;
    int tq = blk % NT;
    int bh = blk / NT;
    int h = bh % NH;
    int b = bh / NH;
    int tid = threadIdx.x;
    int lane = tid & 63;
    int wave = tid >> 6;
    int fr = lane & 15, gq = lane >> 4;
    int q0 = tq * QT;

    __shared__ __attribute__((aligned(16))) __bf16 Ks[KT][56];
    __shared__ __attribute__((aligned(16))) __bf16 Vt[HDIM][72];
    __shared__ __attribute__((aligned(16))) __bf16 Ps[4][16][72];

    int qrow = q0 + wave * 16 + fr;
    bf16x8 aq = {};
    if (qrow < NQQ)
        aq = *(const bf16x8*)(QK + ((size_t)(b * NQQ + qrow)) * QKLD + h * HDIM + gq * 8);

    f32x4 o0 = {}, o1 = {};
    float m_r[4] = {-1e30f, -1e30f, -1e30f, -1e30f};
    float l_r[4] = {0.f, 0.f, 0.f, 0.f};
    const float scale = 0.17677669529663687f;

    for (int kt = 0; kt < NT; kt++) {
        int kv0 = kt * KT;
        {
            int r = tid >> 2;
            int c8 = (tid & 3) * 8;
            int kvr = kv0 + r;
            bf16x8 kv_ = {}, vv_ = {};
            if (kvr < NQQ) {
                kv_ = *(const bf16x8*)(QK + ((size_t)(b * NQQ + kvr)) * QKLD + 256 + h * HDIM + c8);
                vv_ = *(const bf16x8*)(V + ((size_t)(b * NQQ + kvr)) * DD + h * HDIM + c8);
            }
            *(bf16x8*)(&Ks[r][c8]) = kv_;
#pragma unroll
            for (int j = 0; j < 8; j++) Vt[c8 + j][r] = vv_[j];
        }
        __syncthreads();

        f32x4 s[4];
#pragma unroll
        for (int f = 0; f < 4; f++) {
            bf16x8 bk = *(const bf16x8*)(&Ks[f * 16 + fr][gq * 8]);
            f32x4 z = {};
            s[f] = __builtin_amdgcn_mfma_f32_16x16x32_bf16(aq, bk, z, 0, 0, 0);
        }
#pragma unroll
        for (int f = 0; f < 4; f++) {
            bool valid = (kv0 + f * 16 + fr) < NQQ;
#pragma unroll
            for (int r = 0; r < 4; r++)
                s[f][r] = valid ? s[f][r] * scale : -1e30f;
        }
        float sc_[4];
#pragma unroll
        for (int r = 0; r < 4; r++) {
            float v = fmaxf(fmaxf(s[0][r], s[1][r]), fmaxf(s[2][r], s[3][r]));
            v = fmaxf(v, __shfl_xor(v, 1));
            v = fmaxf(v, __shfl_xor(v, 2));
            v = fmaxf(v, __shfl_xor(v, 4));
            v = fmaxf(v, __shfl_xor(v, 8));
            float mn = fmaxf(m_r[r], v);
            sc_[r] = expf(m_r[r] - mn);
            m_r[r] = mn;
        }
        float rs[4] = {0.f, 0.f, 0.f, 0.f};
#pragma unroll
        for (int f = 0; f < 4; f++)
#pragma unroll
            for (int r = 0; r < 4; r++) {
                float e = expf(s[f][r] - m_r[r]);
                s[f][r] = e;
                rs[r] += e;
            }
#pragma unroll
        for (int r = 0; r < 4; r++) {
            float v = rs[r];
            v += __shfl_xor(v, 1);
            v += __shfl_xor(v, 2);
            v += __shfl_xor(v, 4);
            v += __shfl_xor(v, 8);
            l_r[r] = l_r[r] * sc_[r] + v;
            o0[r] *= sc_[r];
            o1[r] *= sc_[r];
        }
#pragma unroll
        for (int f = 0; f < 4; f++)
#pragma unroll
            for (int r = 0; r < 4; r++)
                Ps[wave][gq * 4 + r][f * 16 + fr] = (__bf16)s[f][r];
#pragma unroll
        for (int c = 0; c < 2; c++) {
            bf16x8 ap = *(const bf16x8*)(&Ps[wave][fr][c * 32 + gq * 8]);
            bf16x8 bv0 = *(const bf16x8*)(&Vt[fr][c * 32 + gq * 8]);
            bf16x8 bv1 = *(const bf16x8*)(&Vt[16 + fr][c * 32 + gq * 8]);
            o0 = __builtin_amdgcn_mfma_f32_16x16x32_bf16(ap, bv0, o0, 0, 0, 0);
            o1 = __builtin_amdgcn_mfma_f32_16x16x32_bf16(ap, bv1, o1, 0, 0, 0);
        }
        __syncthreads();
    }
#pragma unroll
    for (int r = 0; r < 4; r++) {
        int qr = q0 + wave * 16 + gq * 4 + r;
        if (qr < NQQ) {
            float inv = 1.f / l_r[r];
            O[((size_t)(b * NQQ + qr)) * DD + h * HDIM + fr] = o0[r] * inv;
            O[((size_t)(b * NQQ + qr)) * DD + h * HDIM + 16 + fr] = o1[r] * inv;
        }
    }
}

// ---------------- msdeform v3: 1 query/block, 16B gathers, shfl reduce -------
#define OAW 384

__global__ __launch_bounds__(256) void msdeform3(
    const __bf16* __restrict__ val, const __bf16* __restrict__ oa,
    const float* __restrict__ ref, float* __restrict__ out) {
    int tid = threadIdx.x;
    int row = blockIdx.x;               // flat b*NQQ+q
    int b_ = row / NQQ;

    __shared__ float sx[128], sy[128], sw[128];

    if (tid < 128) {
        int h = tid >> 4;
        int lp = tid & 15;
        int l = lp >> 2;
        float logit = (float)oa[(size_t)row * OAW + 256 + h * 16 + lp];
        float ox = (float)oa[(size_t)row * OAW + h * 32 + lp * 2];
        float oy = (float)oa[(size_t)row * OAW + h * 32 + lp * 2 + 1];
        const float* rp = ref + ((size_t)row * LV + l) * 4;
        float cx = rp[0], cy = rp[1], rw = rp[2], rh = rp[3];
        float mv = logit;
        mv = fmaxf(mv, __shfl_xor(mv, 1));
        mv = fmaxf(mv, __shfl_xor(mv, 2));
        mv = fmaxf(mv, __shfl_xor(mv, 4));
        mv = fmaxf(mv, __shfl_xor(mv, 8));
        float e = expf(logit - mv);
        float sum = e;
        sum += __shfl_xor(sum, 1);
        sum += __shfl_xor(sum, 2);
        sum += __shfl_xor(sum, 4);
        sum += __shfl_xor(sum, 8);
        int Wl = 128 >> l;
        float lx = cx + ox * (1.0f / NP) * rw * 0.5f;
        float ly = cy + oy * (1.0f / NP) * rh * 0.5f;
        sx[tid] = lx * Wl - 0.5f;
        sy[tid] = ly * Wl - 0.5f;       // H == W for all levels
        sw[tid] = e / sum;
    }
    __syncthreads();

    int cpar = tid & 7;
    int dgrp = (tid >> 3) & 3;
    int h = tid >> 5;
    const int stt[4] = {0, 16384, 20480, 21504};
    const __bf16* vb = val + (size_t)b_ * SS * DD + h * HDIM + dgrp * 8;
    float facc[8] = {};
#pragma unroll
    for (int k = 0; k < 8; k++) {
        int combo = cpar * 8 + k;       // 0..63 unique per (lp,tap)
        int lp = combo >> 2;
        int tap = combo & 3;
        int l = lp >> 2;
        int Wl = 128 >> l;
        int cidx = h * 16 + lp;
        float x = sx[cidx], y = sy[cidx], w = sw[cidx];
        float x0f = floorf(x), y0f = floorf(y);
        float dx = x - x0f, dy = y - y0f;
        int xi = (int)x0f + (tap & 1);
        int yi = (int)y0f + (tap >> 1);
        float wt = ((tap & 1) ? dx : 1.f - dx) * ((tap >> 1) ? dy : 1.f - dy) * w;
        if ((xi >= 0) & (xi < Wl) & (yi >= 0) & (yi < Wl)) {
            bf16x8 t = *(const bf16x8*)(vb + (size_t)(stt[l] + yi * Wl + xi) * DD);
#pragma unroll
            for (int e = 0; e < 8; e++) facc[e] += wt * (float)t[e];
        }
    }
#pragma unroll
    for (int e = 0; e < 8; e++) {
        facc[e] += __shfl_xor(facc[e], 1);
        facc[e] += __shfl_xor(facc[e], 2);
        facc[e] += __shfl_xor(facc[e], 4);
    }
    float v = facc[0];
#pragma unroll
    for (int e = 1; e < 8; e++) if (cpar == e) v = facc[e];
    out[(size_t)row * DD + tid] = v;
}

// ---------------- launch ----------------
extern "C" void kernel_launch(void* const* d_in, const int* in_sizes, int n_in,
                              void* d_out, int out_size, void* d_ws, size_t ws_size,
                              hipStream_t stream) {
    const float* query      = (const float*)d_in[0];
    const float* query_pos  = (const float*)d_in[1];
    const float* refpts     = (const float*)d_in[2];
    const float* input_flat = (const float*)d_in[3];
    const float* sa_in_w    = (const float*)d_in[6];
    const float* sa_in_b    = (const float*)d_in[7];
    const float* sa_out_w   = (const float*)d_in[8];
    const float* sa_out_b   = (const float*)d_in[9];
    const float* norm1_g    = (const float*)d_in[10];
    const float* norm1_b    = (const float*)d_in[11];
    const float* value_w    = (const float*)d_in[12];
    const float* value_b    = (const float*)d_in[13];
    const float* off_w      = (const float*)d_in[14];
    const float* off_b      = (const float*)d_in[15];
    const float* aw_w       = (const float*)d_in[16];
    const float* aw_b       = (const float*)d_in[17];
    const float* ca_out_w   = (const float*)d_in[18];
    const float* ca_out_b   = (const float*)d_in[19];
    const float* norm2_g    = (const float*)d_in[20];
    const float* norm2_b    = (const float*)d_in[21];
    const float* lin1_w     = (const float*)d_in[22];
    const float* lin1_b     = (const float*)d_in[23];
    const float* lin2_w     = (const float*)d_in[24];
    const float* lin2_b     = (const float*)d_in[25];
    const float* norm3_g    = (const float*)d_in[26];
    const float* norm3_b    = (const float*)d_in[27];
    float* out = (float*)d_out;

    const int M = BB * NQQ;              // 3600
    const int NE = M * DD;               // 921600
    const size_t slotBytes = (size_t)NE * 4;
    const size_t wElems = 6 * 65536 + 32768 + 65536 + 2 * 524288;
    const size_t wBytes = wElems * 2;
    const size_t bigBytes = (size_t)BB * SS * DD * 2;
    const size_t needBytes = 3 * slotBytes + wBytes + bigBytes;
    if (ws_size < needBytes) {
        float mark = 1000.0f + (float)(ws_size >> 20);
        fillmark<<<(out_size + 255) / 256, 256, 0, stream>>>(out, out_size, mark);
        return;
    }

    char* wsb = (char*)d_ws;
    float* s0 = (float*)(wsb);
    float* s1 = (float*)(wsb + slotBytes);
    float* s2 = (float*)(wsb + 2 * slotBytes);
    __bf16* wb = (__bf16*)(wsb + 3 * slotBytes);
    __bf16* vbig = (__bf16*)(wsb + 3 * slotBytes + wBytes);

    __bf16* wt_q   = wb;                 // [512][256] combined with wt_k
    __bf16* wt_k   = wb + 65536;
    __bf16* wt_v   = wb + 131072;
    __bf16* wt_sa  = wb + 196608;
    __bf16* wt_val = wb + 262144;
    __bf16* wt_off = wb + 327680;        // [384][256] combined with wt_aw
    __bf16* wt_aw  = wb + 393216;
    __bf16* wt_ca  = wb + 425984;
    __bf16* wt_l1  = wb + 491520;
    __bf16* wt_l2  = wb + 1015808;

    TPtrs tp;
    tp.s[0] = sa_in_w;          tp.d[0] = wt_q;
    tp.s[1] = sa_in_w + 65536;  tp.d[1] = wt_k;
    tp.s[2] = sa_in_w + 131072; tp.d[2] = wt_v;
    tp.s[3] = sa_out_w;         tp.d[3] = wt_sa;
    tp.s[4] = value_w;          tp.d[4] = wt_val;
    tp.s[5] = off_w;            tp.d[5] = wt_off;
    tp.s[6] = aw_w;             tp.d[6] = wt_aw;
    tp.s[7] = ca_out_w;         tp.d[7] = wt_ca;
    tp.s[8] = lin1_w;           tp.d[8] = wt_l1;
    tp.s[9] = lin2_w;           tp.d[9] = wt_l2;
    transp_all<<<1504, dim3(32, 8), 0, stream>>>(tp);

    __bf16* qkbuf = (__bf16*)s1;     // [M][512]
    __bf16* Vp = (__bf16*)s2;        // [M][256]
    __bf16* oabuf = (__bf16*)s1;     // [M][384] (after attn, qk dead)

    const int mt = (M + BM - 1) / BM;    // 57
    const int BIG = 1 << 30;

    // fused: value proj + QK proj(+query_pos) + V proj in one launch
    fused_head<<<NVALB + NQKB + NVB, 256, 0, stream>>>(
        input_flat, wt_val, value_b, vbig,
        query, query_pos, wt_q, sa_in_b, qkbuf, wt_v, Vp, M);
    // attention -> s0 (own kernel, small LDS => high occupancy)
    sa_attn_mfma<<<BB * NH * NT, 256, 0, stream>>>(qkbuf, Vp, s0);
    // sa projection + residual(query) + LN1 fused -> s2 (x1)
    mfma_gemm<float, float, 0, 4, true><<<dim3(1, mt), 256, 0, stream>>>(
        s0, nullptr, wt_sa, sa_out_b, sa_out_b, BIG,
        query, norm1_g, norm1_b, s2, M, DD, DD);
    // off+aw projection (fused +query_pos), N=384 -> s1
    mfma_gemm<float, __bf16, 0, 1, false><<<dim3(6, mt), 256, 0, stream>>>(
        s2, query_pos, wt_off, off_b, aw_b, 256,
        nullptr, nullptr, nullptr, oabuf, M, OAW, DD);
    // deformable sampling -> s0
    msdeform3<<<M, 256, 0, stream>>>(vbig, oabuf, refpts, s0);
    // ca projection + residual(x1) + LN2 fused -> s1 (x2)
    mfma_gemm<float, float, 0, 4, true><<<dim3(1, mt), 256, 0, stream>>>(
        s0, nullptr, wt_ca, ca_out_b, ca_out_b, BIG,
        s2, norm2_g, norm2_b, s1, M, DD, DD);
    // ffn1 -> vbig (bf16, relu), NSUB=2
    mfma_gemm<float, __bf16, 1, 2, false><<<dim3(16, mt), 256, 0, stream>>>(
        s1, nullptr, wt_l1, lin1_b, lin1_b, BIG,
        nullptr, nullptr, nullptr, vbig, M, DFF, DD);
    // ffn2 -> s0 (NSUB=1, 228 blocks — LNF here regressed, see R16)
    mfma_gemm<__bf16, float, 0, 1, false><<<dim3(4, mt), 256, 0, stream>>>(
        vbig, nullptr, wt_l2, lin2_b, lin2_b, BIG,
        nullptr, nullptr, nullptr, s0, M, DD, DFF);
    // out = LN(x2 + ffn2)
    ln_res<<<M, DD, 0, stream>>>(s1, s0, norm3_g, norm3_b, out);
}

// Round 18
// 193.176 us; speedup vs baseline: 1.1442x; 1.0547x over previous
//
#include <hip/hip_runtime.h>
#include <hip/hip_bf16.h>

#define DD   256
#define NH   8
#define HDIM 32
#define LV   4
#define NP   4
#define DFF  2048
#define BB   4
#define NQQ  900
#define SS   21760

typedef __bf16 bf16x8 __attribute__((ext_vector_type(8)));
typedef __bf16 bf16x2 __attribute__((ext_vector_type(2)));
typedef float  f32x4  __attribute__((ext_vector_type(4)));

__device__ inline void stval(float* p, float v) { *p = v; }
__device__ inline void stval(__bf16* p, float v) { *p = (__bf16)v; }

__device__ __forceinline__ void gload16(const void* g, void* l) {
    __builtin_amdgcn_global_load_lds(
        (const __attribute__((address_space(1))) void*)g,
        (__attribute__((address_space(3))) void*)l, 16, 0, 0);
}

// ============ all weight transposes in ONE launch ============================
struct TPtrs {
    const float* s[10];
    __bf16* d[10];
};

__global__ void transp_all(TPtrs P) {
    const int Ks[10] = {256, 256, 256, 256, 256, 256, 256, 256, 256, 2048};
    const int Ns[10] = {256, 256, 256, 256, 256, 256, 128, 256, 2048, 256};
    const int tiles[10] = {64, 64, 64, 64, 64, 64, 32, 64, 512, 512};
    int t = blockIdx.x;
    int j = 0, base = 0;
    while (t >= base + tiles[j]) { base += tiles[j]; j++; }
    int lt = t - base;
    int K = Ks[j], N = Ns[j];
    int tn = N >> 5;
    int nb = (lt % tn) * 32, kb = (lt / tn) * 32;
    const float* W = P.s[j];
    __bf16* Wt = P.d[j];
    __shared__ float tbuf[32][33];
    for (int i = threadIdx.y; i < 32; i += 8)
        tbuf[i][threadIdx.x] = W[(size_t)(kb + i) * N + nb + threadIdx.x];
    __syncthreads();
    for (int i = threadIdx.y; i < 32; i += 8)
        Wt[(size_t)(nb + i) * K + kb + threadIdx.x] = (__bf16)tbuf[threadIdx.x][i];
}

// ============ GEMM body: C = (A[+A2]) @ Wt^T + bias [opt LN fuse] ===========
// lda/ldb: row strides of A and Wt; kbeg: K offset (split-K); K: segment len.
#define BM 64
#define BN 64
#define BKK 64

template <typename AT, typename OT, int RELU, int NSUB, bool LNF>
__device__ __forceinline__ void gemm_body(
    int bx, int by, char* ldsraw,
    const AT* __restrict__ A, const float* __restrict__ A2,
    const __bf16* __restrict__ Wt,
    const float* __restrict__ bias, const float* __restrict__ bias2, int nsplit,
    const float* __restrict__ res, const float* __restrict__ lng,
    const float* __restrict__ lnb,
    OT* __restrict__ C, int M, int N, int K, int lda, int ldb, int kbeg) {
    int tid = threadIdx.x;
    int lane = tid & 63;
    int wave = tid >> 6;
    int wr = wave >> 1, wc = wave & 1;
    int m0 = by * BM;
    int n0 = bx * (BN * NSUB);

    __bf16* As = (__bf16*)ldsraw;
    __bf16* Bs = (__bf16*)(ldsraw + BM * BKK * 2);
    float* rsum  = (float*)(ldsraw + BM * BKK * 2 + NSUB * BN * BKK * 2);
    float* rsum2 = rsum + 128;

    f32x4 acc[NSUB][2][2] = {};

    int srow = tid >> 2;
    int sq = tid & 3;
    int u0 = sq << 1;
    int p0 = (u0 ^ (srow & 7)) * 8;
    int p1 = ((u0 + 1) ^ (srow & 7)) * 8;
    int fr = lane & 15, gq = lane >> 4;

    for (int k0 = 0; k0 < K; k0 += BKK) {
        {
            int gm = m0 + srow;
            bf16x8 v0 = {}, v1 = {};
            if (gm < M) {
                if constexpr (sizeof(AT) == 4) {
                    const float* ap = (const float*)A + (size_t)gm * lda + kbeg + k0 + sq * 16;
                    f32x4 f0 = *(const f32x4*)(ap + 0);
                    f32x4 f1 = *(const f32x4*)(ap + 4);
                    f32x4 f2 = *(const f32x4*)(ap + 8);
                    f32x4 f3 = *(const f32x4*)(ap + 12);
                    if (A2) {
                        const float* ap2 = A2 + (size_t)gm * lda + kbeg + k0 + sq * 16;
                        f0 += *(const f32x4*)(ap2 + 0);
                        f1 += *(const f32x4*)(ap2 + 4);
                        f2 += *(const f32x4*)(ap2 + 8);
                        f3 += *(const f32x4*)(ap2 + 12);
                    }
#pragma unroll
                    for (int e = 0; e < 4; e++) {
                        v0[e] = (__bf16)f0[e]; v0[e + 4] = (__bf16)f1[e];
                        v1[e] = (__bf16)f2[e]; v1[e + 4] = (__bf16)f3[e];
                    }
                } else {
                    const __bf16* ap = (const __bf16*)A + (size_t)gm * lda + kbeg + k0 + sq * 16;
                    v0 = *(const bf16x8*)(ap);
                    v1 = *(const bf16x8*)(ap + 8);
                }
            }
            *(bf16x8*)(&As[srow * 64 + p0]) = v0;
            *(bf16x8*)(&As[srow * 64 + p1]) = v1;
        }
#pragma unroll
        for (int ns = 0; ns < NSUB; ns++) {
            int gn = n0 + ns * BN + srow;
            const __bf16* bp = Wt + (size_t)gn * ldb + kbeg + k0 + sq * 16;
            bf16x8 w0 = *(const bf16x8*)(bp);
            bf16x8 w1 = *(const bf16x8*)(bp + 8);
            *(bf16x8*)(&Bs[ns * BN * BKK + srow * 64 + p0]) = w0;
            *(bf16x8*)(&Bs[ns * BN * BKK + srow * 64 + p1]) = w1;
        }
        __syncthreads();
#pragma unroll
        for (int ks = 0; ks < 2; ks++) {
            bf16x8 a[2];
#pragma unroll
            for (int i = 0; i < 2; i++) {
                int ma = wr * 32 + i * 16 + fr;
                a[i] = *(const bf16x8*)(&As[ma * 64 + ((ks * 4 + gq) ^ (ma & 7)) * 8]);
            }
#pragma unroll
            for (int ns = 0; ns < NSUB; ns++) {
                bf16x8 b[2];
#pragma unroll
                for (int j = 0; j < 2; j++) {
                    int nb = wc * 32 + j * 16 + fr;
                    b[j] = *(const bf16x8*)(&Bs[ns * BN * BKK + nb * 64 + ((ks * 4 + gq) ^ (nb & 7)) * 8]);
                }
#pragma unroll
                for (int i = 0; i < 2; i++)
#pragma unroll
                    for (int j = 0; j < 2; j++)
                        acc[ns][i][j] = __builtin_amdgcn_mfma_f32_16x16x32_bf16(a[i], b[j], acc[ns][i][j], 0, 0, 0);
            }
        }
        __syncthreads();
    }
    int orow = gq * 4;
    if constexpr (!LNF) {
#pragma unroll
        for (int ns = 0; ns < NSUB; ns++)
#pragma unroll
            for (int i = 0; i < 2; i++)
#pragma unroll
                for (int j = 0; j < 2; j++) {
                    int gn = n0 + ns * BN + wc * 32 + j * 16 + fr;
                    float bv = bias ? ((gn < nsplit) ? bias[gn] : bias2[gn - nsplit]) : 0.f;
#pragma unroll
                    for (int r = 0; r < 4; r++) {
                        int gm = m0 + wr * 32 + i * 16 + orow + r;
                        if (gm < M) {
                            float v = acc[ns][i][j][r] + bv;
                            if (RELU) v = fmaxf(v, 0.f);
                            stval(C + (size_t)gm * N + gn, v);
                        }
                    }
                }
    } else {
        float part[2][4] = {};
#pragma unroll
        for (int ns = 0; ns < NSUB; ns++)
#pragma unroll
            for (int i = 0; i < 2; i++)
#pragma unroll
                for (int j = 0; j < 2; j++) {
                    int gn = ns * BN + wc * 32 + j * 16 + fr;
                    float bv = bias[gn];
#pragma unroll
                    for (int r = 0; r < 4; r++) {
                        int gm = m0 + wr * 32 + i * 16 + orow + r;
                        float rv = (gm < M) ? res[(size_t)gm * 256 + gn] : 0.f;
                        float x = acc[ns][i][j][r] + bv + rv;
                        acc[ns][i][j][r] = x;
                        part[i][r] += x;
                    }
                }
#pragma unroll
        for (int i = 0; i < 2; i++)
#pragma unroll
            for (int r = 0; r < 4; r++) {
                float v = part[i][r];
                v += __shfl_xor(v, 1);
                v += __shfl_xor(v, 2);
                v += __shfl_xor(v, 4);
                v += __shfl_xor(v, 8);
                part[i][r] = v;
            }
        if (fr == 0) {
#pragma unroll
            for (int i = 0; i < 2; i++)
#pragma unroll
                for (int r = 0; r < 4; r++)
                    rsum[(wr * 32 + i * 16 + orow + r) * 2 + wc] = part[i][r];
        }
        __syncthreads();
        float mean[2][4];
#pragma unroll
        for (int i = 0; i < 2; i++)
#pragma unroll
            for (int r = 0; r < 4; r++) {
                int rl = wr * 32 + i * 16 + orow + r;
                mean[i][r] = (rsum[rl * 2] + rsum[rl * 2 + 1]) * (1.f / 256.f);
            }
        float p2[2][4] = {};
#pragma unroll
        for (int ns = 0; ns < NSUB; ns++)
#pragma unroll
            for (int i = 0; i < 2; i++)
#pragma unroll
                for (int j = 0; j < 2; j++)
#pragma unroll
                    for (int r = 0; r < 4; r++) {
                        float d = acc[ns][i][j][r] - mean[i][r];
                        p2[i][r] += d * d;
                    }
#pragma unroll
        for (int i = 0; i < 2; i++)
#pragma unroll
            for (int r = 0; r < 4; r++) {
                float v = p2[i][r];
                v += __shfl_xor(v, 1);
                v += __shfl_xor(v, 2);
                v += __shfl_xor(v, 4);
                v += __shfl_xor(v, 8);
                p2[i][r] = v;
            }
        if (fr == 0) {
#pragma unroll
            for (int i = 0; i < 2; i++)
#pragma unroll
                for (int r = 0; r < 4; r++)
                    rsum2[(wr * 32 + i * 16 + orow + r) * 2 + wc] = p2[i][r];
        }
        __syncthreads();
        float rstd[2][4];
#pragma unroll
        for (int i = 0; i < 2; i++)
#pragma unroll
            for (int r = 0; r < 4; r++) {
                int rl = wr * 32 + i * 16 + orow + r;
                float var = (rsum2[rl * 2] + rsum2[rl * 2 + 1]) * (1.f / 256.f);
                rstd[i][r] = rsqrtf(var + 1e-5f);
            }
#pragma unroll
        for (int ns = 0; ns < NSUB; ns++)
#pragma unroll
            for (int i = 0; i < 2; i++)
#pragma unroll
                for (int j = 0; j < 2; j++) {
                    int gn = ns * BN + wc * 32 + j * 16 + fr;
                    float gv = lng[gn], bev = lnb[gn];
#pragma unroll
                    for (int r = 0; r < 4; r++) {
                        int gm = m0 + wr * 32 + i * 16 + orow + r;
                        if (gm < M) {
                            float y = (acc[ns][i][j][r] - mean[i][r]) * rstd[i][r] * gv + bev;
                            stval(C + (size_t)gm * 256 + gn, y);
                        }
                    }
                }
    }
}

template <typename AT, typename OT, int RELU, int NSUB, bool LNF>
__global__ __launch_bounds__(256) void mfma_gemm(
    const AT* __restrict__ A, const float* __restrict__ A2,
    const __bf16* __restrict__ Wt,
    const float* __restrict__ bias, const float* __restrict__ bias2, int nsplit,
    const float* __restrict__ res, const float* __restrict__ lng,
    const float* __restrict__ lnb,
    OT* __restrict__ C, int M, int N, int K) {
    __shared__ __attribute__((aligned(16))) char lds[BM * BKK * 2 + NSUB * BN * BKK * 2 + (LNF ? 1024 : 0)];
    gemm_body<AT, OT, RELU, NSUB, LNF>(blockIdx.x, blockIdx.y, lds, A, A2, Wt,
                                       bias, bias2, nsplit, res, lng, lnb, C, M, N, K, K, K, 0);
}

// ============ ffn2 split-K: two K=1024 halves in ONE launch =================
__global__ __launch_bounds__(256) void ffn2_split(
    const __bf16* __restrict__ vbig, const __bf16* __restrict__ wt_l2,
    float* __restrict__ p1, float* __restrict__ p2, int M) {
    __shared__ __attribute__((aligned(16))) char lds[BM * BKK * 2 + BN * BKK * 2];
    int bx = blockIdx.x;
    int col = bx & 3;
    int half = bx >> 2;
    float* outp = half ? p2 : p1;
    gemm_body<__bf16, float, 0, 1, false>(col, blockIdx.y, lds,
        vbig, nullptr, wt_l2, nullptr, nullptr, 1 << 30,
        nullptr, nullptr, nullptr, outp, M, 256, 1024, 2048, 2048, half * 1024);
}

// ============ value body v5: 2-deep A prefetch + counted vmcnt ==============
__device__ __forceinline__ void value_body(
    int bx, char* ldsraw,
    const float* __restrict__ A, const __bf16* __restrict__ Wt,
    const float* __restrict__ bias, __bf16* __restrict__ C) {
    int tid = threadIdx.x;
    int lane = tid & 63;
    int wave = tid >> 6;
    int fr = lane & 15, gq = lane >> 4;
    int m0 = bx * 64;

    __bf16* As = (__bf16*)ldsraw;             // [2][64*64]  16 KB
    __bf16* Bq = (__bf16*)(ldsraw + 16384);   // [2][4][64*64] 64 KB

    f32x4 acc[4][4] = {};

    int srow = tid >> 2;
    int sq = tid & 3;
    int u0 = sq << 1;
    int p0 = (u0 ^ (srow & 7)) * 8;
    int p1 = ((u0 + 1) ^ (srow & 7)) * 8;

    int c_row = lane >> 3;
    int c_u = lane & 7;
    int gu = c_u ^ c_row;
    const __bf16* bsrc0 = Wt + (size_t)(wave * 64 + c_row) * 256 + gu * 8;
    const float* aptr = A + (size_t)(m0 + srow) * 256 + sq * 16;

    f32x4 fA0, fA1, fA2, fA3;
    f32x4 fB0, fB1, fB2, fB3;

#define LOADA(s0_, s1_, s2_, s3_, off)                          \
    { const float* _p = aptr + (off);                           \
      s0_ = *(const f32x4*)(_p + 0);  s1_ = *(const f32x4*)(_p + 4); \
      s2_ = *(const f32x4*)(_p + 8);  s3_ = *(const f32x4*)(_p + 12); }

#define WRITEA(buf, s0_, s1_, s2_, s3_)                         \
    { bf16x8 _v0, _v1;                                          \
      _Pragma("unroll")                                         \
      for (int e = 0; e < 4; e++) {                             \
          _v0[e] = (__bf16)s0_[e]; _v0[e + 4] = (__bf16)s1_[e]; \
          _v1[e] = (__bf16)s2_[e]; _v1[e + 4] = (__bf16)s3_[e]; \
      }                                                         \
      *(bf16x8*)(&As[(buf) * 4096 + srow * 64 + p0]) = _v0;     \
      *(bf16x8*)(&As[(buf) * 4096 + srow * 64 + p1]) = _v1; }

#define ISSUEB(step, buf)                                       \
    { const __bf16* _b = bsrc0 + (step) * 64;                   \
      _Pragma("unroll")                                         \
      for (int c = 0; c < 8; c++)                               \
          gload16(_b + (size_t)c * 8 * 256, &Bq[((buf) * 4 + wave) * 4096 + c * 512]); }

#define MFMAS(buf)                                              \
    _Pragma("unroll")                                           \
    for (int ks = 0; ks < 2; ks++) {                            \
        bf16x8 a[4], b[4];                                      \
        _Pragma("unroll")                                       \
        for (int i = 0; i < 4; i++) {                           \
            int ma = i * 16 + fr;                               \
            a[i] = *(const bf16x8*)(&As[(buf) * 4096 + ma * 64 + ((ks * 4 + gq) ^ (ma & 7)) * 8]); \
            b[i] = *(const bf16x8*)(&Bq[((buf) * 4 + wave) * 4096 + ma * 64 + ((ks * 4 + gq) ^ (ma & 7)) * 8]); \
        }                                                       \
        _Pragma("unroll")                                       \
        for (int i = 0; i < 4; i++)                             \
            _Pragma("unroll")                                   \
            for (int j = 0; j < 4; j++)                         \
                acc[i][j] = __builtin_amdgcn_mfma_f32_16x16x32_bf16(a[i], b[j], acc[i][j], 0, 0, 0); \
    }

    LOADA(fA0, fA1, fA2, fA3, 0);
    __builtin_amdgcn_sched_barrier(0);
    ISSUEB(0, 0);
    LOADA(fB0, fB1, fB2, fB3, 64);
    asm volatile("s_waitcnt vmcnt(12)" ::: "memory");
    __builtin_amdgcn_sched_barrier(0);
    WRITEA(0, fA0, fA1, fA2, fA3);
    asm volatile("s_waitcnt lgkmcnt(0)" ::: "memory");
    __builtin_amdgcn_s_barrier();

    ISSUEB(1, 1);
    LOADA(fA0, fA1, fA2, fA3, 128);
    asm volatile("s_waitcnt vmcnt(16)" ::: "memory");
    __builtin_amdgcn_sched_barrier(0);
    MFMAS(0);
    asm volatile("s_waitcnt vmcnt(12)" ::: "memory");
    __builtin_amdgcn_sched_barrier(0);
    WRITEA(1, fB0, fB1, fB2, fB3);
    asm volatile("s_waitcnt lgkmcnt(0)" ::: "memory");
    __builtin_amdgcn_s_barrier();

    ISSUEB(2, 0);
    LOADA(fB0, fB1, fB2, fB3, 192);
    asm volatile("s_waitcnt vmcnt(16)" ::: "memory");
    __builtin_amdgcn_sched_barrier(0);
    MFMAS(1);
    asm volatile("s_waitcnt vmcnt(12)" ::: "memory");
    __builtin_amdgcn_sched_barrier(0);
    WRITEA(0, fA0, fA1, fA2, fA3);
    asm volatile("s_waitcnt lgkmcnt(0)" ::: "memory");
    __builtin_amdgcn_s_barrier();

    ISSUEB(3, 1);
    asm volatile("s_waitcnt vmcnt(12)" ::: "memory");
    __builtin_amdgcn_sched_barrier(0);
    MFMAS(0);
    asm volatile("s_waitcnt vmcnt(8)" ::: "memory");
    __builtin_amdgcn_sched_barrier(0);
    WRITEA(1, fB0, fB1, fB2, fB3);
    asm volatile("s_waitcnt lgkmcnt(0)" ::: "memory");
    __builtin_amdgcn_s_barrier();

    asm volatile("s_waitcnt vmcnt(0)" ::: "memory");
    __builtin_amdgcn_sched_barrier(0);
    MFMAS(1);

#undef LOADA
#undef WRITEA
#undef ISSUEB
#undef MFMAS

#pragma unroll
    for (int i = 0; i < 4; i++)
#pragma unroll
        for (int j = 0; j < 4; j++) {
            int gn = wave * 64 + j * 16 + fr;
            float bv = bias[gn];
#pragma unroll
            for (int r = 0; r < 4; r++) {
                int gm = m0 + i * 16 + gq * 4 + r;
                C[(size_t)gm * 256 + gn] = (__bf16)(acc[i][j][r] + bv);
            }
        }
}

// ============ fused head: value proj + QK proj + V proj in one launch =======
#define NVALB 1360
#define NQKB  228
#define NVB   228

__global__ __launch_bounds__(256) void fused_head(
    const float* __restrict__ input_flat, const __bf16* __restrict__ wt_val,
    const float* __restrict__ value_b, __bf16* __restrict__ vbig,
    const float* __restrict__ query, const float* __restrict__ query_pos,
    const __bf16* __restrict__ wt_q, const float* __restrict__ sa_in_b,
    __bf16* __restrict__ qkbuf, const __bf16* __restrict__ wt_v,
    __bf16* __restrict__ Vp, int M) {
    __shared__ __attribute__((aligned(16))) char lds[81920];
    int bx = blockIdx.x;
    if (bx < NVALB) {
        value_body(bx, lds, input_flat, wt_val, value_b, vbig);
    } else if (bx < NVALB + NQKB) {
        int b2 = bx - NVALB;
        gemm_body<float, __bf16, 0, 2, false>(b2 & 3, b2 >> 2, lds,
            query, query_pos, wt_q, sa_in_b, sa_in_b, 1 << 30,
            nullptr, nullptr, nullptr, qkbuf, M, 512, 256, 256, 256, 0);
    } else {
        int b2 = bx - NVALB - NQKB;
        gemm_body<float, __bf16, 0, 1, false>(b2 & 3, b2 >> 2, lds,
            query, nullptr, wt_v, sa_in_b + 512, sa_in_b, 1 << 30,
            nullptr, nullptr, nullptr, Vp, M, 256, 256, 256, 256, 0);
    }
}

__global__ void fillmark(float* o, int n, float v) {
    int i = blockIdx.x * blockDim.x + threadIdx.x;
    if (i < n) o[i] = v;
}

// ---------------- 3-input residual + bias + layernorm (LN3) ----------------
__global__ void ln_res3(const float* a, const float* b1, const float* b2,
                        const float* cb, const float* g, const float* be,
                        float* o) {
    int row = blockIdx.x;
    int t = threadIdx.x;
    float x = a[(size_t)row * DD + t] + b1[(size_t)row * DD + t] +
              b2[(size_t)row * DD + t] + cb[t];
    __shared__ float red[DD];
    red[t] = x;
    __syncthreads();
    for (int s = 128; s > 0; s >>= 1) {
        if (t < s) red[t] += red[t + s];
        __syncthreads();
    }
    float m = red[0] * (1.f / DD);
    __syncthreads();
    float d0 = x - m;
    red[t] = d0 * d0;
    __syncthreads();
    for (int s = 128; s > 0; s >>= 1) {
        if (t < s) red[t] += red[t + s];
        __syncthreads();
    }
    float v = red[0] * (1.f / DD);
    o[(size_t)row * DD + t] = d0 * rsqrtf(v + 1e-5f) * g[t] + be[t];
}

// ---------------- MFMA flash self-attention (QK packed, stride 512) ---------
#define QT 64
#define KT 64
#define NT ((NQQ + KT - 1) / KT)   // 15
#define QKLD 512

__global__ __launch_bounds__(256) void sa_attn_mfma(
    const __bf16* __restrict__ QK, const __bf16* __restrict__ V,
    float* __restrict__ O) {
    int blk = blockIdx.x;
    int tq = blk % NT;
    int bh = blk / NT;
    int h = bh % NH;
    int b = bh / NH;
    int tid = threadIdx.x;
    int lane = tid & 63;
    int wave = tid >> 6;
    int fr = lane & 15, gq = lane >> 4;
    int q0 = tq * QT;

    __shared__ __attribute__((aligned(16))) __bf16 Ks[KT][56];
    __shared__ __attribute__((aligned(16))) __bf16 Vt[HDIM][72];
    __shared__ __attribute__((aligned(16))) __bf16 Ps[4][16][72];

    int qrow = q0 + wave * 16 + fr;
    bf16x8 aq = {};
    if (qrow < NQQ)
        aq = *(const bf16x8*)(QK + ((size_t)(b * NQQ + qrow)) * QKLD + h * HDIM + gq * 8);

    f32x4 o0 = {}, o1 = {};
    float m_r[4] = {-1e30f, -1e30f, -1e30f, -1e30f};
    float l_r[4] = {0.f, 0.f, 0.f, 0.f};
    const float scale = 0.17677669529663687f;

    for (int kt = 0; kt < NT; kt++) {
        int kv0 = kt * KT;
        {
            int r = tid >> 2;
            int c8 = (tid & 3) * 8;
            int kvr = kv0 + r;
            bf16x8 kv_ = {}, vv_ = {};
            if (kvr < NQQ) {
                kv_ = *(const bf16x8*)(QK + ((size_t)(b * NQQ + kvr)) * QKLD + 256 + h * HDIM + c8);
                vv_ = *(const bf16x8*)(V + ((size_t)(b * NQQ + kvr)) * DD + h * HDIM + c8);
            }
            *(bf16x8*)(&Ks[r][c8]) = kv_;
#pragma unroll
            for (int j = 0; j < 8; j++) Vt[c8 + j][r] = vv_[j];
        }
        __syncthreads();

        f32x4 s[4];
#pragma unroll
        for (int f = 0; f < 4; f++) {
            bf16x8 bk = *(const bf16x8*)(&Ks[f * 16 + fr][gq * 8]);
            f32x4 z = {};
            s[f] = __builtin_amdgcn_mfma_f32_16x16x32_bf16(aq, bk, z, 0, 0, 0);
        }
#pragma unroll
        for (int f = 0; f < 4; f++) {
            bool valid = (kv0 + f * 16 + fr) < NQQ;
#pragma unroll
            for (int r = 0; r < 4; r++)
                s[f][r] = valid ? s[f][r] * scale : -1e30f;
        }
        float sc_[4];
#pragma unroll
        for (int r = 0; r < 4; r++) {
            float v = fmaxf(fmaxf(s[0][r], s[1][r]), fmaxf(s[2][r], s[3][r]));
            v = fmaxf(v, __shfl_xor(v, 1));
            v = fmaxf(v, __shfl_xor(v, 2));
            v = fmaxf(v, __shfl_xor(v, 4));
            v = fmaxf(v, __shfl_xor(v, 8));
            float mn = fmaxf(m_r[r], v);
            sc_[r] = expf(m_r[r] - mn);
            m_r[r] = mn;
        }
        float rs[4] = {0.f, 0.f, 0.f, 0.f};
#pragma unroll
        for (int f = 0; f < 4; f++)
#pragma unroll
            for (int r = 0; r < 4; r++) {
                float e = expf(s[f][r] - m_r[r]);
                s[f][r] = e;
                rs[r] += e;
            }
#pragma unroll
        for (int r = 0; r < 4; r++) {
            float v = rs[r];
            v += __shfl_xor(v, 1);
            v += __shfl_xor(v, 2);
            v += __shfl_xor(v, 4);
            v += __shfl_xor(v, 8);
            l_r[r] = l_r[r] * sc_[r] + v;
            o0[r] *= sc_[r];
            o1[r] *= sc_[r];
        }
#pragma unroll
        for (int f = 0; f < 4; f++)
#pragma unroll
            for (int r = 0; r < 4; r++)
                Ps[wave][gq * 4 + r][f * 16 + fr] = (__bf16)s[f][r];
#pragma unroll
        for (int c = 0; c < 2; c++) {
            bf16x8 ap = *(const bf16x8*)(&Ps[wave][fr][c * 32 + gq * 8]);
            bf16x8 bv0 = *(const bf16x8*)(&Vt[fr][c * 32 + gq * 8]);
            bf16x8 bv1 = *(const bf16x8*)(&Vt[16 + fr][c * 32 + gq * 8]);
            o0 = __builtin_amdgcn_mfma_f32_16x16x32_bf16(ap, bv0, o0, 0, 0, 0);
            o1 = __builtin_amdgcn_mfma_f32_16x16x32_bf16(ap, bv1, o1, 0, 0, 0);
        }
        __syncthreads();
    }
#pragma unroll
    for (int r = 0; r < 4; r++) {
        int qr = q0 + wave * 16 + gq * 4 + r;
        if (qr < NQQ) {
            float inv = 1.f / l_r[r];
            O[((size_t)(b * NQQ + qr)) * DD + h * HDIM + fr] = o0[r] * inv;
            O[((size_t)(b * NQQ + qr)) * DD + h * HDIM + 16 + fr] = o1[r] * inv;
        }
    }
}

// ---------------- msdeform v3: 1 query/block, 16B gathers, shfl reduce -------
#define OAW 384

__global__ __launch_bounds__(256) void msdeform3(
    const __bf16* __restrict__ val, const __bf16* __restrict__ oa,
    const float* __restrict__ ref, float* __restrict__ out) {
    int tid = threadIdx.x;
    int row = blockIdx.x;               // flat b*NQQ+q
    int b_ = row / NQQ;

    __shared__ float sx[128], sy[128], sw[128];

    if (tid < 128) {
        int h = tid >> 4;
        int lp = tid & 15;
        int l = lp >> 2;
        float logit = (float)oa[(size_t)row * OAW + 256 + h * 16 + lp];
        float ox = (float)oa[(size_t)row * OAW + h * 32 + lp * 2];
        float oy = (float)oa[(size_t)row * OAW + h * 32 + lp * 2 + 1];
        const float* rp = ref + ((size_t)row * LV + l) * 4;
        float cx = rp[0], cy = rp[1], rw = rp[2], rh = rp[3];
        float mv = logit;
        mv = fmaxf(mv, __shfl_xor(mv, 1));
        mv = fmaxf(mv, __shfl_xor(mv, 2));
        mv = fmaxf(mv, __shfl_xor(mv, 4));
        mv = fmaxf(mv, __shfl_xor(mv, 8));
        float e = expf(logit - mv);
        float sum = e;
        sum += __shfl_xor(sum, 1);
        sum += __shfl_xor(sum, 2);
        sum += __shfl_xor(sum, 4);
        sum += __shfl_xor(sum, 8);
        int Wl = 128 >> l;
        float lx = cx + ox * (1.0f / NP) * rw * 0.5f;
        float ly = cy + oy * (1.0f / NP) * rh * 0.5f;
        sx[tid] = lx * Wl - 0.5f;
        sy[tid] = ly * Wl - 0.5f;       // H == W for all levels
        sw[tid] = e / sum;
    }
    __syncthreads();

    int cpar = tid & 7;
    int dgrp = (tid >> 3) & 3;
    int h = tid >> 5;
    const int stt[4] = {0, 16384, 20480, 21504};
    const __bf16* vb = val + (size_t)b_ * SS * DD + h * HDIM + dgrp * 8;
    float facc[8] = {};
#pragma unroll
    for (int k = 0; k < 8; k++) {
        int combo = cpar * 8 + k;       // 0..63 unique per (lp,tap)
        int lp = combo >> 2;
        int tap = combo & 3;
        int l = lp >> 2;
        int Wl = 128 >> l;
        int cidx = h * 16 + lp;
        float x = sx[cidx], y = sy[cidx], w = sw[cidx];
        float x0f = floorf(x), y0f = floorf(y);
        float dx = x - x0f, dy = y - y0f;
        int xi = (int)x0f + (tap & 1);
        int yi = (int)y0f + (tap >> 1);
        float wt = ((tap & 1) ? dx : 1.f - dx) * ((tap >> 1) ? dy : 1.f - dy) * w;
        if ((xi >= 0) & (xi < Wl) & (yi >= 0) & (yi < Wl)) {
            bf16x8 t = *(const bf16x8*)(vb + (size_t)(stt[l] + yi * Wl + xi) * DD);
#pragma unroll
            for (int e = 0; e < 8; e++) facc[e] += wt * (float)t[e];
        }
    }
#pragma unroll
    for (int e = 0; e < 8; e++) {
        facc[e] += __shfl_xor(facc[e], 1);
        facc[e] += __shfl_xor(facc[e], 2);
        facc[e] += __shfl_xor(facc[e], 4);
    }
    float v = facc[0];
#pragma unroll
    for (int e = 1; e < 8; e++) if (cpar == e) v = facc[e];
    out[(size_t)row * DD + tid] = v;
}

// ---------------- launch ----------------
extern "C" void kernel_launch(void* const* d_in, const int* in_sizes, int n_in,
                              void* d_out, int out_size, void* d_ws, size_t ws_size,
                              hipStream_t stream) {
    const float* query      = (const float*)d_in[0];
    const float* query_pos  = (const float*)d_in[1];
    const float* refpts     = (const float*)d_in[2];
    const float* input_flat = (const float*)d_in[3];
    const float* sa_in_w    = (const float*)d_in[6];
    const float* sa_in_b    = (const float*)d_in[7];
    const float* sa_out_w   = (const float*)d_in[8];
    const float* sa_out_b   = (const float*)d_in[9];
    const float* norm1_g    = (const float*)d_in[10];
    const float* norm1_b    = (const float*)d_in[11];
    const float* value_w    = (const float*)d_in[12];
    const float* value_b    = (const float*)d_in[13];
    const float* off_w      = (const float*)d_in[14];
    const float* off_b      = (const float*)d_in[15];
    const float* aw_w       = (const float*)d_in[16];
    const float* aw_b       = (const float*)d_in[17];
    const float* ca_out_w   = (const float*)d_in[18];
    const float* ca_out_b   = (const float*)d_in[19];
    const float* norm2_g    = (const float*)d_in[20];
    const float* norm2_b    = (const float*)d_in[21];
    const float* lin1_w     = (const float*)d_in[22];
    const float* lin1_b     = (const float*)d_in[23];
    const float* lin2_w     = (const float*)d_in[24];
    const float* lin2_b     = (const float*)d_in[25];
    const float* norm3_g    = (const float*)d_in[26];
    const float* norm3_b    = (const float*)d_in[27];
    float* out = (float*)d_out;

    const int M = BB * NQQ;              // 3600
    const int NE = M * DD;               // 921600
    const size_t slotBytes = (size_t)NE * 4;
    const size_t wElems = 6 * 65536 + 32768 + 65536 + 2 * 524288;
    const size_t wBytes = wElems * 2;
    const size_t bigBytes = (size_t)BB * SS * DD * 2;
    const size_t needBytes = 4 * slotBytes + wBytes + bigBytes;
    if (ws_size < needBytes) {
        float mark = 1000.0f + (float)(ws_size >> 20);
        fillmark<<<(out_size + 255) / 256, 256, 0, stream>>>(out, out_size, mark);
        return;
    }

    char* wsb = (char*)d_ws;
    float* s0 = (float*)(wsb);
    float* s1 = (float*)(wsb + slotBytes);
    float* s2 = (float*)(wsb + 2 * slotBytes);
    float* s3 = (float*)(wsb + 3 * slotBytes);
    __bf16* wb = (__bf16*)(wsb + 4 * slotBytes);
    __bf16* vbig = (__bf16*)(wsb + 4 * slotBytes + wBytes);

    __bf16* wt_q   = wb;                 // [512][256] combined with wt_k
    __bf16* wt_k   = wb + 65536;
    __bf16* wt_v   = wb + 131072;
    __bf16* wt_sa  = wb + 196608;
    __bf16* wt_val = wb + 262144;
    __bf16* wt_off = wb + 327680;        // [384][256] combined with wt_aw
    __bf16* wt_aw  = wb + 393216;
    __bf16* wt_ca  = wb + 425984;
    __bf16* wt_l1  = wb + 491520;
    __bf16* wt_l2  = wb + 1015808;

    TPtrs tp;
    tp.s[0] = sa_in_w;          tp.d[0] = wt_q;
    tp.s[1] = sa_in_w + 65536;  tp.d[1] = wt_k;
    tp.s[2] = sa_in_w + 131072; tp.d[2] = wt_v;
    tp.s[3] = sa_out_w;         tp.d[3] = wt_sa;
    tp.s[4] = value_w;          tp.d[4] = wt_val;
    tp.s[5] = off_w;            tp.d[5] = wt_off;
    tp.s[6] = aw_w;             tp.d[6] = wt_aw;
    tp.s[7] = ca_out_w;         tp.d[7] = wt_ca;
    tp.s[8] = lin1_w;           tp.d[8] = wt_l1;
    tp.s[9] = lin2_w;           tp.d[9] = wt_l2;
    transp_all<<<1504, dim3(32, 8), 0, stream>>>(tp);

    __bf16* qkbuf = (__bf16*)s1;     // [M][512]
    __bf16* Vp = (__bf16*)s2;        // [M][256]
    __bf16* oabuf = (__bf16*)s1;     // [M][384] (after attn, qk dead)

    const int mt = (M + BM - 1) / BM;    // 57
    const int BIG = 1 << 30;

    // fused: value proj + QK proj(+query_pos) + V proj in one launch
    fused_head<<<NVALB + NQKB + NVB, 256, 0, stream>>>(
        input_flat, wt_val, value_b, vbig,
        query, query_pos, wt_q, sa_in_b, qkbuf, wt_v, Vp, M);
    // attention -> s0
    sa_attn_mfma<<<BB * NH * NT, 256, 0, stream>>>(qkbuf, Vp, s0);
    // sa projection + residual(query) + LN1 fused -> s3 (x1)
    mfma_gemm<float, float, 0, 4, true><<<dim3(1, mt), 256, 0, stream>>>(
        s0, nullptr, wt_sa, sa_out_b, sa_out_b, BIG,
        query, norm1_g, norm1_b, s3, M, DD, DD);
    // off+aw projection (fused +query_pos), N=384 -> s1
    mfma_gemm<float, __bf16, 0, 1, false><<<dim3(6, mt), 256, 0, stream>>>(
        s3, query_pos, wt_off, off_b, aw_b, 256,
        nullptr, nullptr, nullptr, oabuf, M, OAW, DD);
    // deformable sampling -> s0
    msdeform3<<<M, 256, 0, stream>>>(vbig, oabuf, refpts, s0);
    // ca projection + residual(x1=s3) + LN2 fused -> s1 (x2)
    mfma_gemm<float, float, 0, 4, true><<<dim3(1, mt), 256, 0, stream>>>(
        s0, nullptr, wt_ca, ca_out_b, ca_out_b, BIG,
        s3, norm2_g, norm2_b, s1, M, DD, DD);
    // ffn1 -> vbig (bf16, relu), NSUB=2
    mfma_gemm<float, __bf16, 1, 2, false><<<dim3(16, mt), 256, 0, stream>>>(
        s1, nullptr, wt_l1, lin1_b, lin1_b, BIG,
        nullptr, nullptr, nullptr, vbig, M, DFF, DD);
    // ffn2 split-K: two K=1024 halves, one 456-block launch -> s0, s2
    ffn2_split<<<dim3(8, mt), 256, 0, stream>>>(vbig, wt_l2, s0, s2, M);
    // out = LN(x2 + p1 + p2 + lin2_b)
    ln_res3<<<M, DD, 0, stream>>>(s1, s0, s2, lin2_b, norm3_g, norm3_b, out);
}

// Round 19
// 192.169 us; speedup vs baseline: 1.1502x; 1.0052x over previous
//
#include <hip/hip_runtime.h>
#include <hip/hip_bf16.h>

#define DD   256
#define NH   8
#define HDIM 32
#define LV   4
#define NP   4
#define DFF  2048
#define BB   4
#define NQQ  900
#define SS   21760

typedef __bf16 bf16x8 __attribute__((ext_vector_type(8)));
typedef __bf16 bf16x2 __attribute__((ext_vector_type(2)));
typedef float  f32x4  __attribute__((ext_vector_type(4)));

__device__ inline void stval(float* p, float v) { *p = v; }
__device__ inline void stval(__bf16* p, float v) { *p = (__bf16)v; }

__device__ __forceinline__ void gload16(const void* g, void* l) {
    __builtin_amdgcn_global_load_lds(
        (const __attribute__((address_space(1))) void*)g,
        (__attribute__((address_space(3))) void*)l, 16, 0, 0);
}

// ============ all weight transposes in ONE launch ============================
struct TPtrs {
    const float* s[10];
    __bf16* d[10];
};

__global__ void transp_all(TPtrs P) {
    const int Ks[10] = {256, 256, 256, 256, 256, 256, 256, 256, 256, 2048};
    const int Ns[10] = {256, 256, 256, 256, 256, 256, 128, 256, 2048, 256};
    const int tiles[10] = {64, 64, 64, 64, 64, 64, 32, 64, 512, 512};
    int t = blockIdx.x;
    int j = 0, base = 0;
    while (t >= base + tiles[j]) { base += tiles[j]; j++; }
    int lt = t - base;
    int K = Ks[j], N = Ns[j];
    int tn = N >> 5;
    int nb = (lt % tn) * 32, kb = (lt / tn) * 32;
    const float* W = P.s[j];
    __bf16* Wt = P.d[j];
    __shared__ float tbuf[32][33];
    for (int i = threadIdx.y; i < 32; i += 8)
        tbuf[i][threadIdx.x] = W[(size_t)(kb + i) * N + nb + threadIdx.x];
    __syncthreads();
    for (int i = threadIdx.y; i < 32; i += 8)
        Wt[(size_t)(nb + i) * K + kb + threadIdx.x] = (__bf16)tbuf[threadIdx.x][i];
}

// ============ GEMM body: C = (A[+A2]) @ Wt^T + bias [opt LN fuse] ===========
#define BM 64
#define BN 64
#define BKK 64

template <typename AT, typename OT, int RELU, int NSUB, bool LNF>
__device__ __forceinline__ void gemm_body(
    int bx, int by, char* ldsraw,
    const AT* __restrict__ A, const float* __restrict__ A2,
    const __bf16* __restrict__ Wt,
    const float* __restrict__ bias, const float* __restrict__ bias2, int nsplit,
    const float* __restrict__ res, const float* __restrict__ lng,
    const float* __restrict__ lnb,
    OT* __restrict__ C, int M, int N, int K, int lda, int ldb, int kbeg) {
    int tid = threadIdx.x;
    int lane = tid & 63;
    int wave = tid >> 6;
    int wr = wave >> 1, wc = wave & 1;
    int m0 = by * BM;
    int n0 = bx * (BN * NSUB);

    __bf16* As = (__bf16*)ldsraw;
    __bf16* Bs = (__bf16*)(ldsraw + BM * BKK * 2);
    float* rsum  = (float*)(ldsraw + BM * BKK * 2 + NSUB * BN * BKK * 2);
    float* rsum2 = rsum + 128;

    f32x4 acc[NSUB][2][2] = {};

    int srow = tid >> 2;
    int sq = tid & 3;
    int u0 = sq << 1;
    int p0 = (u0 ^ (srow & 7)) * 8;
    int p1 = ((u0 + 1) ^ (srow & 7)) * 8;
    int fr = lane & 15, gq = lane >> 4;

    for (int k0 = 0; k0 < K; k0 += BKK) {
        {
            int gm = m0 + srow;
            bf16x8 v0 = {}, v1 = {};
            if (gm < M) {
                if constexpr (sizeof(AT) == 4) {
                    const float* ap = (const float*)A + (size_t)gm * lda + kbeg + k0 + sq * 16;
                    f32x4 f0 = *(const f32x4*)(ap + 0);
                    f32x4 f1 = *(const f32x4*)(ap + 4);
                    f32x4 f2 = *(const f32x4*)(ap + 8);
                    f32x4 f3 = *(const f32x4*)(ap + 12);
                    if (A2) {
                        const float* ap2 = A2 + (size_t)gm * lda + kbeg + k0 + sq * 16;
                        f0 += *(const f32x4*)(ap2 + 0);
                        f1 += *(const f32x4*)(ap2 + 4);
                        f2 += *(const f32x4*)(ap2 + 8);
                        f3 += *(const f32x4*)(ap2 + 12);
                    }
#pragma unroll
                    for (int e = 0; e < 4; e++) {
                        v0[e] = (__bf16)f0[e]; v0[e + 4] = (__bf16)f1[e];
                        v1[e] = (__bf16)f2[e]; v1[e + 4] = (__bf16)f3[e];
                    }
                } else {
                    const __bf16* ap = (const __bf16*)A + (size_t)gm * lda + kbeg + k0 + sq * 16;
                    v0 = *(const bf16x8*)(ap);
                    v1 = *(const bf16x8*)(ap + 8);
                }
            }
            *(bf16x8*)(&As[srow * 64 + p0]) = v0;
            *(bf16x8*)(&As[srow * 64 + p1]) = v1;
        }
#pragma unroll
        for (int ns = 0; ns < NSUB; ns++) {
            int gn = n0 + ns * BN + srow;
            const __bf16* bp = Wt + (size_t)gn * ldb + kbeg + k0 + sq * 16;
            bf16x8 w0 = *(const bf16x8*)(bp);
            bf16x8 w1 = *(const bf16x8*)(bp + 8);
            *(bf16x8*)(&Bs[ns * BN * BKK + srow * 64 + p0]) = w0;
            *(bf16x8*)(&Bs[ns * BN * BKK + srow * 64 + p1]) = w1;
        }
        __syncthreads();
#pragma unroll
        for (int ks = 0; ks < 2; ks++) {
            bf16x8 a[2];
#pragma unroll
            for (int i = 0; i < 2; i++) {
                int ma = wr * 32 + i * 16 + fr;
                a[i] = *(const bf16x8*)(&As[ma * 64 + ((ks * 4 + gq) ^ (ma & 7)) * 8]);
            }
#pragma unroll
            for (int ns = 0; ns < NSUB; ns++) {
                bf16x8 b[2];
#pragma unroll
                for (int j = 0; j < 2; j++) {
                    int nb = wc * 32 + j * 16 + fr;
                    b[j] = *(const bf16x8*)(&Bs[ns * BN * BKK + nb * 64 + ((ks * 4 + gq) ^ (nb & 7)) * 8]);
                }
#pragma unroll
                for (int i = 0; i < 2; i++)
#pragma unroll
                    for (int j = 0; j < 2; j++)
                        acc[ns][i][j] = __builtin_amdgcn_mfma_f32_16x16x32_bf16(a[i], b[j], acc[ns][i][j], 0, 0, 0);
            }
        }
        __syncthreads();
    }
    int orow = gq * 4;
    if constexpr (!LNF) {
#pragma unroll
        for (int ns = 0; ns < NSUB; ns++)
#pragma unroll
            for (int i = 0; i < 2; i++)
#pragma unroll
                for (int j = 0; j < 2; j++) {
                    int gn = n0 + ns * BN + wc * 32 + j * 16 + fr;
                    float bv = bias ? ((gn < nsplit) ? bias[gn] : bias2[gn - nsplit]) : 0.f;
#pragma unroll
                    for (int r = 0; r < 4; r++) {
                        int gm = m0 + wr * 32 + i * 16 + orow + r;
                        if (gm < M) {
                            float v = acc[ns][i][j][r] + bv;
                            if (RELU) v = fmaxf(v, 0.f);
                            stval(C + (size_t)gm * N + gn, v);
                        }
                    }
                }
    } else {
        float part[2][4] = {};
#pragma unroll
        for (int ns = 0; ns < NSUB; ns++)
#pragma unroll
            for (int i = 0; i < 2; i++)
#pragma unroll
                for (int j = 0; j < 2; j++) {
                    int gn = ns * BN + wc * 32 + j * 16 + fr;
                    float bv = bias[gn];
#pragma unroll
                    for (int r = 0; r < 4; r++) {
                        int gm = m0 + wr * 32 + i * 16 + orow + r;
                        float rv = (gm < M) ? res[(size_t)gm * 256 + gn] : 0.f;
                        float x = acc[ns][i][j][r] + bv + rv;
                        acc[ns][i][j][r] = x;
                        part[i][r] += x;
                    }
                }
#pragma unroll
        for (int i = 0; i < 2; i++)
#pragma unroll
            for (int r = 0; r < 4; r++) {
                float v = part[i][r];
                v += __shfl_xor(v, 1);
                v += __shfl_xor(v, 2);
                v += __shfl_xor(v, 4);
                v += __shfl_xor(v, 8);
                part[i][r] = v;
            }
        if (fr == 0) {
#pragma unroll
            for (int i = 0; i < 2; i++)
#pragma unroll
                for (int r = 0; r < 4; r++)
                    rsum[(wr * 32 + i * 16 + orow + r) * 2 + wc] = part[i][r];
        }
        __syncthreads();
        float mean[2][4];
#pragma unroll
        for (int i = 0; i < 2; i++)
#pragma unroll
            for (int r = 0; r < 4; r++) {
                int rl = wr * 32 + i * 16 + orow + r;
                mean[i][r] = (rsum[rl * 2] + rsum[rl * 2 + 1]) * (1.f / 256.f);
            }
        float p2[2][4] = {};
#pragma unroll
        for (int ns = 0; ns < NSUB; ns++)
#pragma unroll
            for (int i = 0; i < 2; i++)
#pragma unroll
                for (int j = 0; j < 2; j++)
#pragma unroll
                    for (int r = 0; r < 4; r++) {
                        float d = acc[ns][i][j][r] - mean[i][r];
                        p2[i][r] += d * d;
                    }
#pragma unroll
        for (int i = 0; i < 2; i++)
#pragma unroll
            for (int r = 0; r < 4; r++) {
                float v = p2[i][r];
                v += __shfl_xor(v, 1);
                v += __shfl_xor(v, 2);
                v += __shfl_xor(v, 4);
                v += __shfl_xor(v, 8);
                p2[i][r] = v;
            }
        if (fr == 0) {
#pragma unroll
            for (int i = 0; i < 2; i++)
#pragma unroll
                for (int r = 0; r < 4; r++)
                    rsum2[(wr * 32 + i * 16 + orow + r) * 2 + wc] = p2[i][r];
        }
        __syncthreads();
        float rstd[2][4];
#pragma unroll
        for (int i = 0; i < 2; i++)
#pragma unroll
            for (int r = 0; r < 4; r++) {
                int rl = wr * 32 + i * 16 + orow + r;
                float var = (rsum2[rl * 2] + rsum2[rl * 2 + 1]) * (1.f / 256.f);
                rstd[i][r] = rsqrtf(var + 1e-5f);
            }
#pragma unroll
        for (int ns = 0; ns < NSUB; ns++)
#pragma unroll
            for (int i = 0; i < 2; i++)
#pragma unroll
                for (int j = 0; j < 2; j++) {
                    int gn = ns * BN + wc * 32 + j * 16 + fr;
                    float gv = lng[gn], bev = lnb[gn];
#pragma unroll
                    for (int r = 0; r < 4; r++) {
                        int gm = m0 + wr * 32 + i * 16 + orow + r;
                        if (gm < M) {
                            float y = (acc[ns][i][j][r] - mean[i][r]) * rstd[i][r] * gv + bev;
                            stval(C + (size_t)gm * 256 + gn, y);
                        }
                    }
                }
    }
}

template <typename AT, typename OT, int RELU, int NSUB, bool LNF>
__global__ __launch_bounds__(256) void mfma_gemm(
    const AT* __restrict__ A, const float* __restrict__ A2,
    const __bf16* __restrict__ Wt,
    const float* __restrict__ bias, const float* __restrict__ bias2, int nsplit,
    const float* __restrict__ res, const float* __restrict__ lng,
    const float* __restrict__ lnb,
    OT* __restrict__ C, int M, int N, int K) {
    __shared__ __attribute__((aligned(16))) char lds[BM * BKK * 2 + NSUB * BN * BKK * 2 + (LNF ? 1024 : 0)];
    gemm_body<AT, OT, RELU, NSUB, LNF>(blockIdx.x, blockIdx.y, lds, A, A2, Wt,
                                       bias, bias2, nsplit, res, lng, lnb, C, M, N, K, K, K, 0);
}

// ============ ffn2 split-K: two K=1024 halves in ONE launch =================
__global__ __launch_bounds__(256) void ffn2_split(
    const __bf16* __restrict__ vbig, const __bf16* __restrict__ wt_l2,
    float* __restrict__ p1, float* __restrict__ p2, int M) {
    __shared__ __attribute__((aligned(16))) char lds[BM * BKK * 2 + BN * BKK * 2];
    int bx = blockIdx.x;
    int col = bx & 3;
    int half = bx >> 2;
    float* outp = half ? p2 : p1;
    gemm_body<__bf16, float, 0, 1, false>(col, blockIdx.y, lds,
        vbig, nullptr, wt_l2, nullptr, nullptr, 1 << 30,
        nullptr, nullptr, nullptr, outp, M, 256, 1024, 2048, 2048, half * 1024);
}

// ============ value body v6: A dbuf + wave-private SINGLE B (48KB LDS) ======
// B (Wt) is L2-resident (~250cy): single-buffered, refilled by each wave right
// after its own MFMAs (wave-private => no barrier needed for B). 3 blocks/CU.
__device__ __forceinline__ void value_body(
    int bx, char* ldsraw,
    const float* __restrict__ A, const __bf16* __restrict__ Wt,
    const float* __restrict__ bias, __bf16* __restrict__ C) {
    int tid = threadIdx.x;
    int lane = tid & 63;
    int wave = tid >> 6;
    int fr = lane & 15, gq = lane >> 4;
    int m0 = bx * 64;

    __bf16* As = (__bf16*)ldsraw;             // [2][64*64]  16 KB
    __bf16* Bq = (__bf16*)(ldsraw + 16384);   // [4][64*64]  32 KB (single)

    f32x4 acc[4][4] = {};

    int srow = tid >> 2;
    int sq = tid & 3;
    int u0 = sq << 1;
    int p0 = (u0 ^ (srow & 7)) * 8;
    int p1 = ((u0 + 1) ^ (srow & 7)) * 8;

    int c_row = lane >> 3;
    int c_u = lane & 7;
    int gu = c_u ^ c_row;
    const __bf16* bsrc0 = Wt + (size_t)(wave * 64 + c_row) * 256 + gu * 8;
    const float* aptr = A + (size_t)(m0 + srow) * 256 + sq * 16;

    f32x4 fA0, fA1, fA2, fA3;
    f32x4 fB0, fB1, fB2, fB3;

#define LOADA(s0_, s1_, s2_, s3_, off)                          \
    { const float* _p = aptr + (off);                           \
      s0_ = *(const f32x4*)(_p + 0);  s1_ = *(const f32x4*)(_p + 4); \
      s2_ = *(const f32x4*)(_p + 8);  s3_ = *(const f32x4*)(_p + 12); }

#define WRITEA(buf, s0_, s1_, s2_, s3_)                         \
    { bf16x8 _v0, _v1;                                          \
      _Pragma("unroll")                                         \
      for (int e = 0; e < 4; e++) {                             \
          _v0[e] = (__bf16)s0_[e]; _v0[e + 4] = (__bf16)s1_[e]; \
          _v1[e] = (__bf16)s2_[e]; _v1[e + 4] = (__bf16)s3_[e]; \
      }                                                         \
      *(bf16x8*)(&As[(buf) * 4096 + srow * 64 + p0]) = _v0;     \
      *(bf16x8*)(&As[(buf) * 4096 + srow * 64 + p1]) = _v1; }

#define ISSUEB(step)                                            \
    { const __bf16* _b = bsrc0 + (step) * 64;                   \
      _Pragma("unroll")                                         \
      for (int c = 0; c < 8; c++)                               \
          gload16(_b + (size_t)c * 8 * 256, &Bq[wave * 4096 + c * 512]); }

#define MFMAS(buf)                                              \
    _Pragma("unroll")                                           \
    for (int ks = 0; ks < 2; ks++) {                            \
        bf16x8 a[4], b[4];                                      \
        _Pragma("unroll")                                       \
        for (int i = 0; i < 4; i++) {                           \
            int ma = i * 16 + fr;                               \
            a[i] = *(const bf16x8*)(&As[(buf) * 4096 + ma * 64 + ((ks * 4 + gq) ^ (ma & 7)) * 8]); \
            b[i] = *(const bf16x8*)(&Bq[wave * 4096 + ma * 64 + ((ks * 4 + gq) ^ (ma & 7)) * 8]); \
        }                                                       \
        _Pragma("unroll")                                       \
        for (int i = 0; i < 4; i++)                             \
            _Pragma("unroll")                                   \
            for (int j = 0; j < 4; j++)                         \
                acc[i][j] = __builtin_amdgcn_mfma_f32_16x16x32_bf16(a[i], b[j], acc[i][j], 0, 0, 0); \
    }

    // ---- prologue ----
    LOADA(fA0, fA1, fA2, fA3, 0);            // A0
    __builtin_amdgcn_sched_barrier(0);
    ISSUEB(0);                               // B0
    LOADA(fB0, fB1, fB2, fB3, 64);           // A1
    asm volatile("s_waitcnt vmcnt(12)" ::: "memory");   // A0 done (B0+A1 fly)
    __builtin_amdgcn_sched_barrier(0);
    WRITEA(0, fA0, fA1, fA2, fA3);
    asm volatile("s_waitcnt lgkmcnt(0)" ::: "memory");
    __builtin_amdgcn_s_barrier();

    // ---- step 0 (buf 0) ----
    asm volatile("s_waitcnt vmcnt(4)" ::: "memory");    // B0 done (A1 remains)
    __builtin_amdgcn_sched_barrier(0);
    MFMAS(0);
    __builtin_amdgcn_sched_barrier(0);
    ISSUEB(1);                               // refill own B quadrant
    LOADA(fA0, fA1, fA2, fA3, 128);          // A2
    asm volatile("s_waitcnt vmcnt(12)" ::: "memory");   // A1 regs ready
    __builtin_amdgcn_sched_barrier(0);
    WRITEA(1, fB0, fB1, fB2, fB3);
    asm volatile("s_waitcnt lgkmcnt(0)" ::: "memory");
    __builtin_amdgcn_s_barrier();

    // ---- step 1 (buf 1) ----
    asm volatile("s_waitcnt vmcnt(4)" ::: "memory");    // B1 done (A2 remains)
    __builtin_amdgcn_sched_barrier(0);
    MFMAS(1);
    __builtin_amdgcn_sched_barrier(0);
    ISSUEB(2);
    LOADA(fB0, fB1, fB2, fB3, 192);          // A3
    asm volatile("s_waitcnt vmcnt(12)" ::: "memory");   // A2 regs ready
    __builtin_amdgcn_sched_barrier(0);
    WRITEA(0, fA0, fA1, fA2, fA3);
    asm volatile("s_waitcnt lgkmcnt(0)" ::: "memory");
    __builtin_amdgcn_s_barrier();

    // ---- step 2 (buf 0) ----
    asm volatile("s_waitcnt vmcnt(4)" ::: "memory");    // B2 done (A3 remains)
    __builtin_amdgcn_sched_barrier(0);
    MFMAS(0);
    __builtin_amdgcn_sched_barrier(0);
    ISSUEB(3);
    asm volatile("s_waitcnt vmcnt(8)" ::: "memory");    // A3 regs ready (B3 flies)
    __builtin_amdgcn_sched_barrier(0);
    WRITEA(1, fB0, fB1, fB2, fB3);
    asm volatile("s_waitcnt lgkmcnt(0)" ::: "memory");
    __builtin_amdgcn_s_barrier();

    // ---- step 3 (buf 1) ----
    asm volatile("s_waitcnt vmcnt(0)" ::: "memory");    // B3 done
    __builtin_amdgcn_sched_barrier(0);
    MFMAS(1);

#undef LOADA
#undef WRITEA
#undef ISSUEB
#undef MFMAS

#pragma unroll
    for (int i = 0; i < 4; i++)
#pragma unroll
        for (int j = 0; j < 4; j++) {
            int gn = wave * 64 + j * 16 + fr;
            float bv = bias[gn];
#pragma unroll
            for (int r = 0; r < 4; r++) {
                int gm = m0 + i * 16 + gq * 4 + r;
                C[(size_t)gm * 256 + gn] = (__bf16)(acc[i][j][r] + bv);
            }
        }
}

// ============ fused head: value proj + QK proj + V proj in one launch =======
#define NVALB 1360
#define NQKB  228
#define NVB   228

__global__ __launch_bounds__(256) void fused_head(
    const float* __restrict__ input_flat, const __bf16* __restrict__ wt_val,
    const float* __restrict__ value_b, __bf16* __restrict__ vbig,
    const float* __restrict__ query, const float* __restrict__ query_pos,
    const __bf16* __restrict__ wt_q, const float* __restrict__ sa_in_b,
    __bf16* __restrict__ qkbuf, const __bf16* __restrict__ wt_v,
    __bf16* __restrict__ Vp, int M) {
    __shared__ __attribute__((aligned(16))) char lds[49152];
    int bx = blockIdx.x;
    if (bx < NVALB) {
        value_body(bx, lds, input_flat, wt_val, value_b, vbig);
    } else if (bx < NVALB + NQKB) {
        int b2 = bx - NVALB;
        gemm_body<float, __bf16, 0, 2, false>(b2 & 3, b2 >> 2, lds,
            query, query_pos, wt_q, sa_in_b, sa_in_b, 1 << 30,
            nullptr, nullptr, nullptr, qkbuf, M, 512, 256, 256, 256, 0);
    } else {
        int b2 = bx - NVALB - NQKB;
        gemm_body<float, __bf16, 0, 1, false>(b2 & 3, b2 >> 2, lds,
            query, nullptr, wt_v, sa_in_b + 512, sa_in_b, 1 << 30,
            nullptr, nullptr, nullptr, Vp, M, 256, 256, 256, 256, 0);
    }
}

__global__ void fillmark(float* o, int n, float v) {
    int i = blockIdx.x * blockDim.x + threadIdx.x;
    if (i < n) o[i] = v;
}

// ---------------- 3-input residual + bias + layernorm (LN3) ----------------
__global__ void ln_res3(const float* a, const float* b1, const float* b2,
                        const float* cb, const float* g, const float* be,
                        float* o) {
    int row = blockIdx.x;
    int t = threadIdx.x;
    float x = a[(size_t)row * DD + t] + b1[(size_t)row * DD + t] +
              b2[(size_t)row * DD + t] + cb[t];
    __shared__ float red[DD];
    red[t] = x;
    __syncthreads();
    for (int s = 128; s > 0; s >>= 1) {
        if (t < s) red[t] += red[t + s];
        __syncthreads();
    }
    float m = red[0] * (1.f / DD);
    __syncthreads();
    float d0 = x - m;
    red[t] = d0 * d0;
    __syncthreads();
    for (int s = 128; s > 0; s >>= 1) {
        if (t < s) red[t] += red[t + s];
        __syncthreads();
    }
    float v = red[0] * (1.f / DD);
    o[(size_t)row * DD + t] = d0 * rsqrtf(v + 1e-5f) * g[t] + be[t];
}

// ---------------- MFMA flash self-attention (QK packed, stride 512) ---------
#define QT 64
#define KT 64
#define NT ((NQQ + KT - 1) / KT)   // 15
#define QKLD 512

__global__ __launch_bounds__(256) void sa_attn_mfma(
    const __bf16* __restrict__ QK, const __bf16* __restrict__ V,
    float* __restrict__ O) {
    int blk = blockIdx.x;
    int tq = blk % NT;
    int bh = blk / NT;
    int h = bh % NH;
    int b = bh / NH;
    int tid = threadIdx.x;
    int lane = tid & 63;
    int wave = tid >> 6;
    int fr = lane & 15, gq = lane >> 4;
    int q0 = tq * QT;

    __shared__ __attribute__((aligned(16))) __bf16 Ks[KT][56];
    __shared__ __attribute__((aligned(16))) __bf16 Vt[HDIM][72];
    __shared__ __attribute__((aligned(16))) __bf16 Ps[4][16][72];

    int qrow = q0 + wave * 16 + fr;
    bf16x8 aq = {};
    if (qrow < NQQ)
        aq = *(const bf16x8*)(QK + ((size_t)(b * NQQ + qrow)) * QKLD + h * HDIM + gq * 8);

    f32x4 o0 = {}, o1 = {};
    float m_r[4] = {-1e30f, -1e30f, -1e30f, -1e30f};
    float l_r[4] = {0.f, 0.f, 0.f, 0.f};
    const float scale = 0.17677669529663687f;

    for (int kt = 0; kt < NT; kt++) {
        int kv0 = kt * KT;
        {
            int r = tid >> 2;
            int c8 = (tid & 3) * 8;
            int kvr = kv0 + r;
            bf16x8 kv_ = {}, vv_ = {};
            if (kvr < NQQ) {
                kv_ = *(const bf16x8*)(QK + ((size_t)(b * NQQ + kvr)) * QKLD + 256 + h * HDIM + c8);
                vv_ = *(const bf16x8*)(V + ((size_t)(b * NQQ + kvr)) * DD + h * HDIM + c8);
            }
            *(bf16x8*)(&Ks[r][c8]) = kv_;
#pragma unroll
            for (int j = 0; j < 8; j++) Vt[c8 + j][r] = vv_[j];
        }
        __syncthreads();

        f32x4 s[4];
#pragma unroll
        for (int f = 0; f < 4; f++) {
            bf16x8 bk = *(const bf16x8*)(&Ks[f * 16 + fr][gq * 8]);
            f32x4 z = {};
            s[f] = __builtin_amdgcn_mfma_f32_16x16x32_bf16(aq, bk, z, 0, 0, 0);
        }
#pragma unroll
        for (int f = 0; f < 4; f++) {
            bool valid = (kv0 + f * 16 + fr) < NQQ;
#pragma unroll
            for (int r = 0; r < 4; r++)
                s[f][r] = valid ? s[f][r] * scale : -1e30f;
        }
        float sc_[4];
#pragma unroll
        for (int r = 0; r < 4; r++) {
            float v = fmaxf(fmaxf(s[0][r], s[1][r]), fmaxf(s[2][r], s[3][r]));
            v = fmaxf(v, __shfl_xor(v, 1));
            v = fmaxf(v, __shfl_xor(v, 2));
            v = fmaxf(v, __shfl_xor(v, 4));
            v = fmaxf(v, __shfl_xor(v, 8));
            float mn = fmaxf(m_r[r], v);
            sc_[r] = expf(m_r[r] - mn);
            m_r[r] = mn;
        }
        float rs[4] = {0.f, 0.f, 0.f, 0.f};
#pragma unroll
        for (int f = 0; f < 4; f++)
#pragma unroll
            for (int r = 0; r < 4; r++) {
                float e = expf(s[f][r] - m_r[r]);
                s[f][r] = e;
                rs[r] += e;
            }
#pragma unroll
        for (int r = 0; r < 4; r++) {
            float v = rs[r];
            v += __shfl_xor(v, 1);
            v += __shfl_xor(v, 2);
            v += __shfl_xor(v, 4);
            v += __shfl_xor(v, 8);
            l_r[r] = l_r[r] * sc_[r] + v;
            o0[r] *= sc_[r];
            o1[r] *= sc_[r];
        }
#pragma unroll
        for (int f = 0; f < 4; f++)
#pragma unroll
            for (int r = 0; r < 4; r++)
                Ps[wave][gq * 4 + r][f * 16 + fr] = (__bf16)s[f][r];
#pragma unroll
        for (int c = 0; c < 2; c++) {
            bf16x8 ap = *(const bf16x8*)(&Ps[wave][fr][c * 32 + gq * 8]);
            bf16x8 bv0 = *(const bf16x8*)(&Vt[fr][c * 32 + gq * 8]);
            bf16x8 bv1 = *(const bf16x8*)(&Vt[16 + fr][c * 32 + gq * 8]);
            o0 = __builtin_amdgcn_mfma_f32_16x16x32_bf16(ap, bv0, o0, 0, 0, 0);
            o1 = __builtin_amdgcn_mfma_f32_16x16x32_bf16(ap, bv1, o1, 0, 0, 0);
        }
        __syncthreads();
    }
#pragma unroll
    for (int r = 0; r < 4; r++) {
        int qr = q0 + wave * 16 + gq * 4 + r;
        if (qr < NQQ) {
            float inv = 1.f / l_r[r];
            O[((size_t)(b * NQQ + qr)) * DD + h * HDIM + fr] = o0[r] * inv;
            O[((size_t)(b * NQQ + qr)) * DD + h * HDIM + 16 + fr] = o1[r] * inv;
        }
    }
}

// ---------------- msdeform v3: 1 query/block, 16B gathers, shfl reduce -------
#define OAW 384

__global__ __launch_bounds__(256) void msdeform3(
    const __bf16* __restrict__ val, const __bf16* __restrict__ oa,
    const float* __restrict__ ref, float* __restrict__ out) {
    int tid = threadIdx.x;
    int row = blockIdx.x;               // flat b*NQQ+q
    int b_ = row / NQQ;

    __shared__ float sx[128], sy[128], sw[128];

    if (tid < 128) {
        int h = tid >> 4;
        int lp = tid & 15;
        int l = lp >> 2;
        float logit = (float)oa[(size_t)row * OAW + 256 + h * 16 + lp];
        float ox = (float)oa[(size_t)row * OAW + h * 32 + lp * 2];
        float oy = (float)oa[(size_t)row * OAW + h * 32 + lp * 2 + 1];
        const float* rp = ref + ((size_t)row * LV + l) * 4;
        float cx = rp[0], cy = rp[1], rw = rp[2], rh = rp[3];
        float mv = logit;
        mv = fmaxf(mv, __shfl_xor(mv, 1));
        mv = fmaxf(mv, __shfl_xor(mv, 2));
        mv = fmaxf(mv, __shfl_xor(mv, 4));
        mv = fmaxf(mv, __shfl_xor(mv, 8));
        float e = expf(logit - mv);
        float sum = e;
        sum += __shfl_xor(sum, 1);
        sum += __shfl_xor(sum, 2);
        sum += __shfl_xor(sum, 4);
        sum += __shfl_xor(sum, 8);
        int Wl = 128 >> l;
        float lx = cx + ox * (1.0f / NP) * rw * 0.5f;
        float ly = cy + oy * (1.0f / NP) * rh * 0.5f;
        sx[tid] = lx * Wl - 0.5f;
        sy[tid] = ly * Wl - 0.5f;       // H == W for all levels
        sw[tid] = e / sum;
    }
    __syncthreads();

    int cpar = tid & 7;
    int dgrp = (tid >> 3) & 3;
    int h = tid >> 5;
    const int stt[4] = {0, 16384, 20480, 21504};
    const __bf16* vb = val + (size_t)b_ * SS * DD + h * HDIM + dgrp * 8;
    float facc[8] = {};
#pragma unroll
    for (int k = 0; k < 8; k++) {
        int combo = cpar * 8 + k;       // 0..63 unique per (lp,tap)
        int lp = combo >> 2;
        int tap = combo & 3;
        int l = lp >> 2;
        int Wl = 128 >> l;
        int cidx = h * 16 + lp;
        float x = sx[cidx], y = sy[cidx], w = sw[cidx];
        float x0f = floorf(x), y0f = floorf(y);
        float dx = x - x0f, dy = y - y0f;
        int xi = (int)x0f + (tap & 1);
        int yi = (int)y0f + (tap >> 1);
        float wt = ((tap & 1) ? dx : 1.f - dx) * ((tap >> 1) ? dy : 1.f - dy) * w;
        if ((xi >= 0) & (xi < Wl) & (yi >= 0) & (yi < Wl)) {
            bf16x8 t = *(const bf16x8*)(vb + (size_t)(stt[l] + yi * Wl + xi) * DD);
#pragma unroll
            for (int e = 0; e < 8; e++) facc[e] += wt * (float)t[e];
        }
    }
#pragma unroll
    for (int e = 0; e < 8; e++) {
        facc[e] += __shfl_xor(facc[e], 1);
        facc[e] += __shfl_xor(facc[e], 2);
        facc[e] += __shfl_xor(facc[e], 4);
    }
    float v = facc[0];
#pragma unroll
    for (int e = 1; e < 8; e++) if (cpar == e) v = facc[e];
    out[(size_t)row * DD + tid] = v;
}

// ---------------- launch ----------------
extern "C" void kernel_launch(void* const* d_in, const int* in_sizes, int n_in,
                              void* d_out, int out_size, void* d_ws, size_t ws_size,
                              hipStream_t stream) {
    const float* query      = (const float*)d_in[0];
    const float* query_pos  = (const float*)d_in[1];
    const float* refpts     = (const float*)d_in[2];
    const float* input_flat = (const float*)d_in[3];
    const float* sa_in_w    = (const float*)d_in[6];
    const float* sa_in_b    = (const float*)d_in[7];
    const float* sa_out_w   = (const float*)d_in[8];
    const float* sa_out_b   = (const float*)d_in[9];
    const float* norm1_g    = (const float*)d_in[10];
    const float* norm1_b    = (const float*)d_in[11];
    const float* value_w    = (const float*)d_in[12];
    const float* value_b    = (const float*)d_in[13];
    const float* off_w      = (const float*)d_in[14];
    const float* off_b      = (const float*)d_in[15];
    const float* aw_w       = (const float*)d_in[16];
    const float* aw_b       = (const float*)d_in[17];
    const float* ca_out_w   = (const float*)d_in[18];
    const float* ca_out_b   = (const float*)d_in[19];
    const float* norm2_g    = (const float*)d_in[20];
    const float* norm2_b    = (const float*)d_in[21];
    const float* lin1_w     = (const float*)d_in[22];
    const float* lin1_b     = (const float*)d_in[23];
    const float* lin2_w     = (const float*)d_in[24];
    const float* lin2_b     = (const float*)d_in[25];
    const float* norm3_g    = (const float*)d_in[26];
    const float* norm3_b    = (const float*)d_in[27];
    float* out = (float*)d_out;

    const int M = BB * NQQ;              // 3600
    const int NE = M * DD;               // 921600
    const size_t slotBytes = (size_t)NE * 4;
    const size_t wElems = 6 * 65536 + 32768 + 65536 + 2 * 524288;
    const size_t wBytes = wElems * 2;
    const size_t bigBytes = (size_t)BB * SS * DD * 2;
    const size_t needBytes = 4 * slotBytes + wBytes + bigBytes;
    if (ws_size < needBytes) {
        float mark = 1000.0f + (float)(ws_size >> 20);
        fillmark<<<(out_size + 255) / 256, 256, 0, stream>>>(out, out_size, mark);
        return;
    }

    char* wsb = (char*)d_ws;
    float* s0 = (float*)(wsb);
    float* s1 = (float*)(wsb + slotBytes);
    float* s2 = (float*)(wsb + 2 * slotBytes);
    float* s3 = (float*)(wsb + 3 * slotBytes);
    __bf16* wb = (__bf16*)(wsb + 4 * slotBytes);
    __bf16* vbig = (__bf16*)(wsb + 4 * slotBytes + wBytes);

    __bf16* wt_q   = wb;                 // [512][256] combined with wt_k
    __bf16* wt_k   = wb + 65536;
    __bf16* wt_v   = wb + 131072;
    __bf16* wt_sa  = wb + 196608;
    __bf16* wt_val = wb + 262144;
    __bf16* wt_off = wb + 327680;        // [384][256] combined with wt_aw
    __bf16* wt_aw  = wb + 393216;
    __bf16* wt_ca  = wb + 425984;
    __bf16* wt_l1  = wb + 491520;
    __bf16* wt_l2  = wb + 1015808;

    TPtrs tp;
    tp.s[0] = sa_in_w;          tp.d[0] = wt_q;
    tp.s[1] = sa_in_w + 65536;  tp.d[1] = wt_k;
    tp.s[2] = sa_in_w + 131072; tp.d[2] = wt_v;
    tp.s[3] = sa_out_w;         tp.d[3] = wt_sa;
    tp.s[4] = value_w;          tp.d[4] = wt_val;
    tp.s[5] = off_w;            tp.d[5] = wt_off;
    tp.s[6] = aw_w;             tp.d[6] = wt_aw;
    tp.s[7] = ca_out_w;         tp.d[7] = wt_ca;
    tp.s[8] = lin1_w;           tp.d[8] = wt_l1;
    tp.s[9] = lin2_w;           tp.d[9] = wt_l2;
    transp_all<<<1504, dim3(32, 8), 0, stream>>>(tp);

    __bf16* qkbuf = (__bf16*)s1;     // [M][512]
    __bf16* Vp = (__bf16*)s2;        // [M][256]
    __bf16* oabuf = (__bf16*)s1;     // [M][384] (after attn, qk dead)

    const int mt = (M + BM - 1) / BM;    // 57
    const int BIG = 1 << 30;

    // fused: value proj + QK proj(+query_pos) + V proj in one launch
    fused_head<<<NVALB + NQKB + NVB, 256, 0, stream>>>(
        input_flat, wt_val, value_b, vbig,
        query, query_pos, wt_q, sa_in_b, qkbuf, wt_v, Vp, M);
    // attention -> s0
    sa_attn_mfma<<<BB * NH * NT, 256, 0, stream>>>(qkbuf, Vp, s0);
    // sa projection + residual(query) + LN1 fused -> s3 (x1)
    mfma_gemm<float, float, 0, 4, true><<<dim3(1, mt), 256, 0, stream>>>(
        s0, nullptr, wt_sa, sa_out_b, sa_out_b, BIG,
        query, norm1_g, norm1_b, s3, M, DD, DD);
    // off+aw projection (fused +query_pos), N=384 -> s1
    mfma_gemm<float, __bf16, 0, 1, false><<<dim3(6, mt), 256, 0, stream>>>(
        s3, query_pos, wt_off, off_b, aw_b, 256,
        nullptr, nullptr, nullptr, oabuf, M, OAW, DD);
    // deformable sampling -> s0
    msdeform3<<<M, 256, 0, stream>>>(vbig, oabuf, refpts, s0);
    // ca projection + residual(x1=s3) + LN2 fused -> s1 (x2)
    mfma_gemm<float, float, 0, 4, true><<<dim3(1, mt), 256, 0, stream>>>(
        s0, nullptr, wt_ca, ca_out_b, ca_out_b, BIG,
        s3, norm2_g, norm2_b, s1, M, DD, DD);
    // ffn1 -> vbig (bf16, relu), NSUB=2
    mfma_gemm<float, __bf16, 1, 2, false><<<dim3(16, mt), 256, 0, stream>>>(
        s1, nullptr, wt_l1, lin1_b, lin1_b, BIG,
        nullptr, nullptr, nullptr, vbig, M, DFF, DD);
    // ffn2 split-K: two K=1024 halves, one 456-block launch -> s0, s2
    ffn2_split<<<dim3(8, mt), 256, 0, stream>>>(vbig, wt_l2, s0, s2, M);
    // out = LN(x2 + p1 + p2 + lin2_b)
    ln_res3<<<M, DD, 0, stream>>>(s1, s0, s2, lin2_b, norm3_g, norm3_b, out);
}